// Round 4
// baseline (4966.132 us; speedup 1.0000x reference)
//
#include <hip/hip_runtime.h>
#include <cstdint>
#include <cstddef>

#define DD 512
#define SLOPE 0.2f

typedef unsigned short bf16;

__device__ __forceinline__ float b2f(unsigned short u){
  union { float f; unsigned int i; } v; v.i = ((unsigned int)u) << 16; return v.f;
}
__device__ __forceinline__ unsigned short f2b(float f){
  union { float f; unsigned int i; } v; v.f = f;
  unsigned int r = v.i + 0x7FFFu + ((v.i >> 16) & 1u);
  return (unsigned short)(r >> 16);
}
__device__ __forceinline__ void unpack8(uint4 u, float* f){
  f[0]=b2f((unsigned short)(u.x & 0xFFFFu)); f[1]=b2f((unsigned short)(u.x >> 16));
  f[2]=b2f((unsigned short)(u.y & 0xFFFFu)); f[3]=b2f((unsigned short)(u.y >> 16));
  f[4]=b2f((unsigned short)(u.z & 0xFFFFu)); f[5]=b2f((unsigned short)(u.z >> 16));
  f[6]=b2f((unsigned short)(u.w & 0xFFFFu)); f[7]=b2f((unsigned short)(u.w >> 16));
}
__device__ __forceinline__ uint4 pack8(const float* f){
  uint4 u;
  u.x = (unsigned int)f2b(f[0]) | ((unsigned int)f2b(f[1]) << 16);
  u.y = (unsigned int)f2b(f[2]) | ((unsigned int)f2b(f[3]) << 16);
  u.z = (unsigned int)f2b(f[4]) | ((unsigned int)f2b(f[5]) << 16);
  u.w = (unsigned int)f2b(f[6]) | ((unsigned int)f2b(f[7]) << 16);
  return u;
}

// ------------------------------------------------------------------
// embedding gather: x[row,:] = bf16(emb[idx(row),:])
__global__ __launch_bounds__(128) void embed_kernel(
    const float* __restrict__ emb, const int* __restrict__ xp, const int* __restrict__ xh,
    bf16* __restrict__ x, int NP, int N)
{
  int row = blockIdx.x; if (row >= N) return;
  int idx = (row < NP) ? xp[row] : xh[row - NP];
  float4 v = ((const float4*)(emb + (size_t)idx * DD))[threadIdx.x];
  ushort4 o; o.x = f2b(v.x); o.y = f2b(v.y); o.z = f2b(v.z); o.w = f2b(v.w);
  ((ushort4*)(x + (size_t)row * DD))[threadIdx.x] = o;
}

// ------------------------------------------------------------------
__global__ void mark_starts(const int* __restrict__ batch, int* __restrict__ starts, int n, int B)
{
  int i = blockIdx.x * blockDim.x + threadIdx.x; if (i >= n) return;
  int b = batch[i];
  if (i == 0) starts[0] = 0;
  else if (batch[i-1] != b) starts[b] = i;
  if (i == n-1) starts[B] = n;
}

__global__ __launch_bounds__(256) void compute_maxlen(
    const int* __restrict__ sp, const int* __restrict__ sh, int B, int* __restrict__ devL)
{
  __shared__ int red[256];
  int tid = threadIdx.x;
  int ml = 0;
  for (int b = tid; b < B; b += 256) ml = max(ml, sp[b+1]-sp[b]);
  red[tid] = ml; __syncthreads();
  for (int s = 128; s; s >>= 1){ if (tid < s) red[tid] = max(red[tid], red[tid+s]); __syncthreads(); }
  if (tid == 0) devL[0] = red[0];
  __syncthreads();
  ml = 0;
  for (int b = tid; b < B; b += 256) ml = max(ml, sh[b+1]-sh[b]);
  red[tid] = ml; __syncthreads();
  for (int s = 128; s; s >>= 1){ if (tid < s) red[tid] = max(red[tid], red[tid+s]); __syncthreads(); }
  if (tid == 0) devL[1] = red[0];
}

// ------------------------------------------------------------------
__global__ void edge_count(const int* __restrict__ ep, const int* __restrict__ eh,
                           int E2P, int E2H, int NP, int N, int* __restrict__ counts)
{
  int e = blockIdx.x * blockDim.x + threadIdx.x;
  int EALL = E2P + E2H + N;
  if (e >= EALL) return;
  int dst;
  if (e < E2P)            dst = ep[E2P + e];
  else if (e < E2P + E2H) dst = NP + eh[E2H + (e - E2P)];
  else                    dst = e - E2P - E2H;
  atomicAdd(&counts[dst], 1);
}

__global__ void edge_fill(const int* __restrict__ ep, const int* __restrict__ eh,
                          int E2P, int E2H, int NP, int N,
                          const int* __restrict__ off, int* __restrict__ cursor,
                          int* __restrict__ csr_src)
{
  int e = blockIdx.x * blockDim.x + threadIdx.x;
  int EALL = E2P + E2H + N;
  if (e >= EALL) return;
  int src, dst;
  if (e < E2P)            { src = ep[e];                 dst = ep[E2P + e]; }
  else if (e < E2P + E2H) { int j = e - E2P; src = NP + eh[j]; dst = NP + eh[E2H + j]; }
  else                    { src = dst = e - E2P - E2H; }
  int pos = atomicAdd(&cursor[dst], 1);
  csr_src[off[dst] + pos] = src;
}

__global__ __launch_bounds__(1024) void exscan(const int* __restrict__ in, int* __restrict__ out, int n)
{
  __shared__ int buf[1024];
  __shared__ int carry;
  int tid = threadIdx.x;
  if (tid == 0) carry = 0;
  __syncthreads();
  for (int base = 0; base < n; base += 1024){
    int x = (base + tid < n) ? in[base + tid] : 0;
    buf[tid] = x; __syncthreads();
    for (int off = 1; off < 1024; off <<= 1){
      int v = (tid >= off) ? buf[tid - off] : 0;
      __syncthreads();
      buf[tid] += v;
      __syncthreads();
    }
    if (base + tid < n) out[base + tid] = carry + buf[tid] - x;
    __syncthreads();
    if (tid == 0) carry += buf[1023];
    __syncthreads();
  }
  if (tid == 0) out[n] = carry;
}

// ------------------------------------------------------------------
// tiled GEMM: C[M,Ncol] = A[M,512] @ W[512,Ncol] (+bias) (+=old C) (relu)
// A is bf16 or f32 (template); C is bf16 or f32; W/bias always f32.
// flags: bit0 = accumulate into C, bit1 = relu at end
template<typename AT, typename CT>
__global__ __launch_bounds__(256) void gemm64(
    const AT* __restrict__ A, const float* __restrict__ W, const float* __restrict__ bias,
    CT* __restrict__ C, int M, int Ncol, int flags)
{
  __shared__ float As[16][65];
  __shared__ float Bs[16][64];
  int tid = threadIdx.x;
  int tx = tid & 15, ty = tid >> 4;
  int row0 = blockIdx.x * 64, col0 = blockIdx.y * 64;
  float acc[4][4] = {};
  int lr = tid >> 2, lk = (tid & 3) * 4;
  int bk = tid >> 4, bn = (tid & 15) * 4;
  for (int k0 = 0; k0 < DD; k0 += 16){
    float a0 = 0.f, a1 = 0.f, a2 = 0.f, a3 = 0.f;
    int gr = row0 + lr;
    if (gr < M){
      if constexpr (sizeof(AT) == 2){
        ushort4 av = *(const ushort4*)(A + (size_t)gr * DD + k0 + lk);
        a0 = b2f(av.x); a1 = b2f(av.y); a2 = b2f(av.z); a3 = b2f(av.w);
      } else {
        float4 av = *(const float4*)(A + (size_t)gr * DD + k0 + lk);
        a0 = av.x; a1 = av.y; a2 = av.z; a3 = av.w;
      }
    }
    As[lk+0][lr] = a0; As[lk+1][lr] = a1; As[lk+2][lr] = a2; As[lk+3][lr] = a3;
    *(float4*)&Bs[bk][bn] = *(const float4*)(W + (size_t)(k0 + bk) * Ncol + col0 + bn);
    __syncthreads();
    #pragma unroll
    for (int k = 0; k < 16; k++){
      float x0 = As[k][ty*4+0], x1 = As[k][ty*4+1], x2 = As[k][ty*4+2], x3 = As[k][ty*4+3];
      float y0 = Bs[k][tx*4+0], y1 = Bs[k][tx*4+1], y2 = Bs[k][tx*4+2], y3 = Bs[k][tx*4+3];
      acc[0][0] += x0*y0; acc[0][1] += x0*y1; acc[0][2] += x0*y2; acc[0][3] += x0*y3;
      acc[1][0] += x1*y0; acc[1][1] += x1*y1; acc[1][2] += x1*y2; acc[1][3] += x1*y3;
      acc[2][0] += x2*y0; acc[2][1] += x2*y1; acc[2][2] += x2*y2; acc[2][3] += x2*y3;
      acc[3][0] += x3*y0; acc[3][1] += x3*y1; acc[3][2] += x3*y2; acc[3][3] += x3*y3;
    }
    __syncthreads();
  }
  #pragma unroll
  for (int i = 0; i < 4; i++){
    int gr = row0 + ty*4 + i; if (gr >= M) continue;
    float r0 = acc[i][0], r1 = acc[i][1], r2 = acc[i][2], r3 = acc[i][3];
    if (bias){
      float4 bv = *(const float4*)(bias + col0 + tx*4);
      r0 += bv.x; r1 += bv.y; r2 += bv.z; r3 += bv.w;
    }
    if constexpr (sizeof(CT) == 2){
      ushort4* cp = (ushort4*)(C + (size_t)gr * Ncol + col0 + tx*4);
      if (flags & 1){
        ushort4 o = *cp;
        r0 += b2f(o.x); r1 += b2f(o.y); r2 += b2f(o.z); r3 += b2f(o.w);
      }
      if (flags & 2){
        r0 = fmaxf(r0, 0.f); r1 = fmaxf(r1, 0.f); r2 = fmaxf(r2, 0.f); r3 = fmaxf(r3, 0.f);
      }
      ushort4 o; o.x = f2b(r0); o.y = f2b(r1); o.z = f2b(r2); o.w = f2b(r3);
      *cp = o;
    } else {
      float4* cp = (float4*)(C + (size_t)gr * Ncol + col0 + tx*4);
      if (flags & 1){
        float4 o = *cp;
        r0 += o.x; r1 += o.y; r2 += o.z; r3 += o.w;
      }
      if (flags & 2){
        r0 = fmaxf(r0, 0.f); r1 = fmaxf(r1, 0.f); r2 = fmaxf(r2, 0.f); r3 = fmaxf(r3, 0.f);
      }
      *cp = make_float4(r0, r1, r2, r3);
    }
  }
}

// ------------------------------------------------------------------
// per-node attention coefficients from bf16 xw
__global__ __launch_bounds__(64) void gat_attn_coeff(
    const bf16* __restrict__ xw, const float* __restrict__ att_src, const float* __restrict__ att_dst,
    float* __restrict__ a_s, float* __restrict__ a_d, int N)
{
  int n = blockIdx.x; if (n >= N) return;
  int lane = threadIdx.x;
  float x[8];
  unpack8(*(const uint4*)(xw + (size_t)n * DD + lane * 8), x);
  const float4* sr = (const float4*)(att_src + lane * 8);
  const float4* dr = (const float4*)(att_dst + lane * 8);
  float4 s0 = sr[0], s1 = sr[1], d0 = dr[0], d1 = dr[1];
  float ps = x[0]*s0.x + x[1]*s0.y + x[2]*s0.z + x[3]*s0.w
           + x[4]*s1.x + x[5]*s1.y + x[6]*s1.z + x[7]*s1.w;
  float pd = x[0]*d0.x + x[1]*d0.y + x[2]*d0.z + x[3]*d0.w
           + x[4]*d1.x + x[5]*d1.y + x[6]*d1.z + x[7]*d1.w;
  for (int off = 1; off < 8; off <<= 1){ ps += __shfl_xor(ps, off); pd += __shfl_xor(pd, off); }
  if ((lane & 7) == 0){
    a_s[n*8 + (lane>>3)] = ps;
    a_d[n*8 + (lane>>3)] = pd;
  }
}

// per-node segment softmax + weighted aggregate; one wave per node
__global__ __launch_bounds__(64) void gat_aggregate(
    const bf16* __restrict__ xw, const float* __restrict__ a_s, const float* __restrict__ a_d,
    const int* __restrict__ csr_off, const int* __restrict__ csr_src,
    const float* __restrict__ bias, bf16* __restrict__ out, int N)
{
  int n = blockIdx.x; if (n >= N) return;
  int lane = threadIdx.x;
  int h = lane >> 3;
  int o0 = csr_off[n], deg = csr_off[n+1] - o0;
  float adh = a_d[n*8 + h];
  float mx = -3.4e38f;
  for (int e = 0; e < deg; e++){
    int s = csr_src[o0 + e];
    float v = a_s[s*8 + h] + adh;
    v = (v >= 0.f) ? v : SLOPE * v;
    mx = fmaxf(mx, v);
  }
  float den = 0.f;
  for (int e = 0; e < deg; e++){
    int s = csr_src[o0 + e];
    float v = a_s[s*8 + h] + adh;
    v = (v >= 0.f) ? v : SLOPE * v;
    den += __expf(v - mx);
  }
  float inv = 1.f / (den + 1e-16f);
  float A[8] = {};
  for (int e = 0; e < deg; e++){
    int s = csr_src[o0 + e];
    float v = a_s[s*8 + h] + adh;
    v = (v >= 0.f) ? v : SLOPE * v;
    float al = __expf(v - mx) * inv;
    float x[8];
    unpack8(*(const uint4*)(xw + (size_t)s * DD + lane * 8), x);
    #pragma unroll
    for (int j = 0; j < 8; j++) A[j] += al * x[j];
  }
  const float4* bq = (const float4*)(bias + lane * 8);
  float4 b0 = bq[0], b1 = bq[1];
  float r[8] = { A[0]+b0.x, A[1]+b0.y, A[2]+b0.z, A[3]+b0.w,
                 A[4]+b1.x, A[5]+b1.y, A[6]+b1.z, A[7]+b1.w };
  *(uint4*)(out + (size_t)n * DD + lane * 8) = pack8(r);
}

// ------------------------------------------------------------------
// cross attention, one block per valid h row
__global__ __launch_bounds__(256) void attn_kernel(
    const bf16* __restrict__ Q, const bf16* __restrict__ K, const bf16* __restrict__ V,
    const int* __restrict__ starts_p, const int* __restrict__ hbatch,
    bf16* __restrict__ phat, int NH)
{
  int i = blockIdx.x; if (i >= NH) return;
  int b = hbatch[i];
  int sp = starts_p[b], lp = starts_p[b+1] - sp;
  __shared__ float qs[DD];
  __shared__ float sc[384];
  __shared__ float red[256];
  int tid = threadIdx.x;
  ushort2 qv = ((const ushort2*)(Q + (size_t)i * DD))[tid];
  qs[tid*2] = b2f(qv.x); qs[tid*2+1] = b2f(qv.y);
  __syncthreads();
  int wid = tid >> 6, lane = tid & 63;
  const float scale = 0.044194173824159216f; // 1/sqrt(512)
  for (int m = wid; m < lp; m += 4){
    float kk[8];
    unpack8(*(const uint4*)(K + (size_t)(sp + m) * DD + lane * 8), kk);
    float4 q0 = ((const float4*)qs)[lane*2], q1 = ((const float4*)qs)[lane*2+1];
    float p = q0.x*kk[0] + q0.y*kk[1] + q0.z*kk[2] + q0.w*kk[3]
            + q1.x*kk[4] + q1.y*kk[5] + q1.z*kk[6] + q1.w*kk[7];
    for (int off = 32; off; off >>= 1) p += __shfl_xor(p, off);
    if (lane == 0) sc[m] = p * scale;
  }
  __syncthreads();
  float mx = -3.4e38f;
  for (int m = tid; m < lp; m += 256) mx = fmaxf(mx, sc[m]);
  red[tid] = mx; __syncthreads();
  for (int s = 128; s; s >>= 1){ if (tid < s) red[tid] = fmaxf(red[tid], red[tid+s]); __syncthreads(); }
  mx = red[0]; __syncthreads();
  float sm = 0.f;
  for (int m = tid; m < lp; m += 256){ float e = __expf(sc[m] - mx); sc[m] = e; sm += e; }
  red[tid] = sm; __syncthreads();
  for (int s = 128; s; s >>= 1){ if (tid < s) red[tid] += red[tid+s]; __syncthreads(); }
  float inv = 1.f / (red[0] + 1e-16f);
  float ax = 0.f, ay = 0.f;
  for (int m = 0; m < lp; m++){
    float a = sc[m] * inv;
    ushort2 vv = ((const ushort2*)(V + (size_t)(sp + m) * DD))[tid];
    ax += a * b2f(vv.x); ay += a * b2f(vv.y);
  }
  ushort2 o; o.x = f2b(ax); o.y = f2b(ay);
  ((ushort2*)(phat + (size_t)i * DD))[tid] = o;
}

// pad-row p_hat: padphat[b,:] = (sum over valid m of V)/Lp  (f32 out)
__global__ __launch_bounds__(256) void vsum_kernel(
    const bf16* __restrict__ V, const int* __restrict__ sp_arr, const int* __restrict__ devL,
    float* __restrict__ padphat)
{
  int b = blockIdx.x, tid = threadIdx.x;
  int sp = sp_arr[b], lp = sp_arr[b+1] - sp;
  float ax = 0.f, ay = 0.f;
  for (int m = 0; m < lp; m++){
    ushort2 vv = ((const ushort2*)(V + (size_t)(sp + m) * DD))[tid];
    ax += b2f(vv.x); ay += b2f(vv.y);
  }
  float invLp = 1.f / (float)devL[0];
  ((float2*)(padphat + (size_t)b * DD))[tid] = make_float2(ax * invLp, ay * invLp);
}

__global__ void prod_kernel(const bf16* __restrict__ a, const bf16* __restrict__ b,
                            bf16* __restrict__ c, size_t n8)
{
  size_t i = (size_t)blockIdx.x * blockDim.x + threadIdx.x;
  if (i >= n8) return;
  float fa[8], fb[8], fc[8];
  unpack8(((const uint4*)a)[i], fa);
  unpack8(((const uint4*)b)[i], fb);
  #pragma unroll
  for (int j = 0; j < 8; j++) fc[j] = fa[j] * fb[j];
  ((uint4*)c)[i] = pack8(fc);
}

// combined w1 sub-blocks: Wp = W1a + W1c, Wh = W1b - W1c (feat = [p, h, p-h, p*h])
__global__ void wcomb_kernel(const float* __restrict__ w1, float* __restrict__ Wp, float* __restrict__ Wh)
{
  int i = blockIdx.x * blockDim.x + threadIdx.x;
  if (i >= DD*DD) return;
  float a = w1[i], b = w1[i + DD*DD], c = w1[i + 2*DD*DD];
  Wp[i] = a + c;
  Wh[i] = b - c;
}

// per-graph max/mean over cmp rows (bf16) + pad-row (f32) replicated (Lh - len) times
__global__ __launch_bounds__(256) void pool_kernel(
    const bf16* __restrict__ cmp, const float* __restrict__ padcmp,
    const int* __restrict__ sh_arr, const int* __restrict__ devL,
    float* __restrict__ smax, float* __restrict__ smean)
{
  int b = blockIdx.x, tid = threadIdx.x;
  int sh = sh_arr[b], lh = sh_arr[b+1] - sh;
  int Lh = devL[1];
  float mxx = -3.4e38f, mxy = -3.4e38f, smx = 0.f, smy = 0.f;
  for (int r = 0; r < lh; r++){
    ushort2 v = ((const ushort2*)(cmp + (size_t)(sh + r) * DD))[tid];
    float vx = b2f(v.x), vy = b2f(v.y);
    mxx = fmaxf(mxx, vx); mxy = fmaxf(mxy, vy);
    smx += vx; smy += vy;
  }
  int npad = Lh - lh;
  if (npad > 0){
    float2 p = ((const float2*)(padcmp + (size_t)b * DD))[tid];
    mxx = fmaxf(mxx, p.x); mxy = fmaxf(mxy, p.y);
    smx += npad * p.x; smy += npad * p.y;
  }
  float invLh = 1.f / (float)Lh;
  ((float2*)(smax + (size_t)b * DD))[tid] = make_float2(mxx, mxy);
  ((float2*)(smean + (size_t)b * DD))[tid] = make_float2(smx * invLh, smy * invLh);
}

// logits: [B,512] @ c2[512,3] + cb2 -> d_out[1..1+3B)
__global__ __launch_bounds__(64) void logits_kernel(
    const float* __restrict__ z1, const float* __restrict__ c2, const float* __restrict__ cb2,
    float* __restrict__ out, int B)
{
  int b = blockIdx.x; int lane = threadIdx.x;
  const float4* zr = (const float4*)(z1 + (size_t)b * DD);
  float4 z0 = zr[lane*2], z1v = zr[lane*2+1];
  float zz[8] = {z0.x, z0.y, z0.z, z0.w, z1v.x, z1v.y, z1v.z, z1v.w};
  float p0 = 0.f, p1 = 0.f, p2 = 0.f;
  #pragma unroll
  for (int j = 0; j < 8; j++){
    int k = lane*8 + j;
    p0 += zz[j] * c2[k*3 + 0];
    p1 += zz[j] * c2[k*3 + 1];
    p2 += zz[j] * c2[k*3 + 2];
  }
  for (int off = 32; off; off >>= 1){
    p0 += __shfl_xor(p0, off); p1 += __shfl_xor(p1, off); p2 += __shfl_xor(p2, off);
  }
  if (lane == 0){
    out[1 + b*3 + 0] = p0 + cb2[0];
    out[1 + b*3 + 1] = p1 + cb2[1];
    out[1 + b*3 + 2] = p2 + cb2[2];
  }
}

// BCE-with-logits mean -> d_out[0]
__global__ __launch_bounds__(256) void loss_kernel(
    const float* __restrict__ dout, const float* __restrict__ label, float* __restrict__ out0, int n)
{
  __shared__ float red[256];
  int tid = threadIdx.x;
  float s = 0.f;
  for (int i = tid; i < n; i += 256){
    float z = dout[1 + i], y = label[i];
    s += fmaxf(z, 0.f) - z*y + log1pf(expf(-fabsf(z)));
  }
  red[tid] = s; __syncthreads();
  for (int st = 128; st; st >>= 1){ if (tid < st) red[tid] += red[tid+st]; __syncthreads(); }
  if (tid == 0) out0[0] = red[0] / (float)n;
}

// ------------------------------------------------------------------
extern "C" void kernel_launch(void* const* d_in, const int* in_sizes, int n_in,
                              void* d_out, int out_size, void* d_ws, size_t ws_size,
                              hipStream_t stream)
{
  const float* emb   = (const float*)d_in[0];
  const float* Wgat  = (const float*)d_in[1];
  const float* att_s = (const float*)d_in[2];
  const float* att_d = (const float*)d_in[3];
  const float* gbias = (const float*)d_in[4];
  const float* Wq    = (const float*)d_in[5];
  const float* Wk    = (const float*)d_in[6];
  const float* Wv    = (const float*)d_in[7];
  const float* w1    = (const float*)d_in[8];
  const float* b1    = (const float*)d_in[9];
  const float* w2    = (const float*)d_in[10];
  const float* b2    = (const float*)d_in[11];
  const float* c1    = (const float*)d_in[12];
  const float* cb1   = (const float*)d_in[13];
  const float* c2    = (const float*)d_in[14];
  const float* cb2   = (const float*)d_in[15];
  const float* label = (const float*)d_in[16];
  const int* xp = (const int*)d_in[17];
  const int* xh = (const int*)d_in[18];
  const int* ep = (const int*)d_in[19];
  const int* eh = (const int*)d_in[20];
  const int* bp = (const int*)d_in[21];
  const int* bh = (const int*)d_in[22];

  const int NP  = in_sizes[17], NH = in_sizes[18];
  const int N   = NP + NH;
  const int E2P = in_sizes[19] / 2, E2H = in_sizes[20] / 2;
  const int EALL = E2P + E2H + N;
  const int B = in_sizes[16] / 3;

  char* wptr = (char*)d_ws;
  auto alloc = [&](size_t bytes) -> void* {
    void* p = (void*)wptr; wptr += (bytes + 255) & ~(size_t)255; return p;
  };
  // big intermediates in bf16 (2B) to halve workspace footprint
  bf16* bufX = (bf16*)alloc((size_t)N  * DD * 2);  // node features / enc
  bf16* bufY = (bf16*)alloc((size_t)N  * DD * 2);  // xw ; later K ; later hidden
  bf16* bufV = (bf16*)alloc((size_t)NP * DD * 2);  // V ; later cmp
  bf16* bufQ = (bf16*)alloc((size_t)NH * DD * 2);  // Q ; later p_hat*h
  bf16* bufP = (bf16*)alloc((size_t)NH * DD * 2);  // p_hat
  float* a_s  = (float*)alloc((size_t)N * 8 * 4);
  float* a_d  = (float*)alloc((size_t)N * 8 * 4);
  int* counts   = (int*)alloc((size_t)N * 4);
  int* csr_off  = (int*)alloc((size_t)(N + 1) * 4);
  int* cursor   = (int*)alloc((size_t)N * 4);
  int* csr_src  = (int*)alloc((size_t)EALL * 4);
  int* starts_p = (int*)alloc((size_t)(B + 1) * 4);
  int* starts_h = (int*)alloc((size_t)(B + 1) * 4);
  int* devL     = (int*)alloc(64);
  float* padphat = (float*)alloc((size_t)B * DD * 4);
  float* padhid  = (float*)alloc((size_t)B * DD * 4);
  float* padcmp  = (float*)alloc((size_t)B * DD * 4);
  float* smax  = (float*)alloc((size_t)B * DD * 4);
  float* smean = (float*)alloc((size_t)B * DD * 4);
  float* z1    = (float*)alloc((size_t)B * DD * 4);
  float* Wpc   = (float*)alloc((size_t)DD * DD * 4);
  float* Whc   = (float*)alloc((size_t)DD * DD * 4);

  hipMemsetAsync(counts, 0, (size_t)N * 4, stream);
  hipMemsetAsync(cursor, 0, (size_t)N * 4, stream);

  embed_kernel<<<N, 128, 0, stream>>>(emb, xp, xh, bufX, NP, N);
  mark_starts<<<(NP + 255)/256, 256, 0, stream>>>(bp, starts_p, NP, B);
  mark_starts<<<(NH + 255)/256, 256, 0, stream>>>(bh, starts_h, NH, B);
  compute_maxlen<<<1, 256, 0, stream>>>(starts_p, starts_h, B, devL);
  edge_count<<<(EALL + 255)/256, 256, 0, stream>>>(ep, eh, E2P, E2H, NP, N, counts);
  exscan<<<1, 1024, 0, stream>>>(counts, csr_off, N);
  edge_fill<<<(EALL + 255)/256, 256, 0, stream>>>(ep, eh, E2P, E2H, NP, N, csr_off, cursor, csr_src);
  wcomb_kernel<<<(DD*DD + 255)/256, 256, 0, stream>>>(w1, Wpc, Whc);

  auto gemmB = [&](const bf16* A, const float* Wm, const float* bias, bf16* Cv, int M, int flags){
    dim3 g((unsigned)((M + 63)/64), DD/64);
    gemm64<bf16, bf16><<<g, 256, 0, stream>>>(A, Wm, bias, Cv, M, DD, flags);
  };
  auto gemmF = [&](const float* A, const float* Wm, const float* bias, float* Cv, int M, int flags){
    dim3 g((unsigned)((M + 63)/64), DD/64);
    gemm64<float, float><<<g, 256, 0, stream>>>(A, Wm, bias, Cv, M, DD, flags);
  };

  // 3 shared-weight GAT layers on the combined graph
  for (int l = 0; l < 3; l++){
    gemmB(bufX, Wgat, nullptr, bufY, N, 0);
    gat_attn_coeff<<<N, 64, 0, stream>>>(bufY, att_s, att_d, a_s, a_d, N);
    gat_aggregate<<<N, 64, 0, stream>>>(bufY, a_s, a_d, csr_off, csr_src, gbias, bufX, N);
  }

  const bf16* h_enc = bufX + (size_t)NP * DD;
  gemmB(h_enc, Wq, nullptr, bufQ, NH, 0);
  gemmB(bufX,  Wk, nullptr, bufY, NP, 0);   // K
  gemmB(bufX,  Wv, nullptr, bufV, NP, 0);   // V
  attn_kernel<<<NH, 256, 0, stream>>>(bufQ, bufY, bufV, starts_p, bh, bufP, NH);
  vsum_kernel<<<B, 256, 0, stream>>>(bufV, starts_p, devL, padphat);

  size_t n8 = (size_t)NH * (DD/8);
  prod_kernel<<<(unsigned)((n8 + 255)/256), 256, 0, stream>>>(bufP, h_enc, bufQ, n8);

  bf16* hid = bufY;                        // K is dead
  gemmB(bufP, Wpc, b1, hid, NH, 0);
  gemmB(h_enc, Whc, nullptr, hid, NH, 1);
  gemmB(bufQ, w1 + (size_t)3*DD*DD, nullptr, hid, NH, 1 | 2);  // W1d block, + relu
  bf16* cmp = bufV;                        // V is dead
  gemmB(hid, w2, b2, cmp, NH, 0);

  gemmF(padphat, Wpc, b1, padhid, B, 2);   // pad rows: feat = [p,0,p,0]
  gemmF(padhid, w2, b2, padcmp, B, 0);

  pool_kernel<<<B, 256, 0, stream>>>(cmp, padcmp, starts_h, devL, smax, smean);

  gemmF(smax,  c1,                 cb1,     z1, B, 0);
  gemmF(smean, c1 + (size_t)DD*DD, nullptr, z1, B, 1 | 2);
  logits_kernel<<<B, 64, 0, stream>>>(z1, c2, cb2, (float*)d_out, B);
  loss_kernel<<<1, 256, 0, stream>>>((float*)d_out, label, (float*)d_out, B * 3);
}

// Round 5
// 2276.650 us; speedup vs baseline: 2.1813x; 2.1813x over previous
//
#include <hip/hip_runtime.h>
#include <cstdint>
#include <cstddef>

#define DD 512
#define SLOPE 0.2f

typedef unsigned short bf16;
typedef __attribute__((ext_vector_type(8))) short short8v;  // 8 bf16 (4 VGPRs)
typedef __attribute__((ext_vector_type(4))) float f32x4;

__device__ __forceinline__ float b2f(unsigned short u){
  union { float f; unsigned int i; } v; v.i = ((unsigned int)u) << 16; return v.f;
}
__device__ __forceinline__ unsigned short f2b(float f){
  union { float f; unsigned int i; } v; v.f = f;
  unsigned int r = v.i + 0x7FFFu + ((v.i >> 16) & 1u);
  return (unsigned short)(r >> 16);
}
__device__ __forceinline__ void unpack8(uint4 u, float* f){
  f[0]=b2f((unsigned short)(u.x & 0xFFFFu)); f[1]=b2f((unsigned short)(u.x >> 16));
  f[2]=b2f((unsigned short)(u.y & 0xFFFFu)); f[3]=b2f((unsigned short)(u.y >> 16));
  f[4]=b2f((unsigned short)(u.z & 0xFFFFu)); f[5]=b2f((unsigned short)(u.z >> 16));
  f[6]=b2f((unsigned short)(u.w & 0xFFFFu)); f[7]=b2f((unsigned short)(u.w >> 16));
}
__device__ __forceinline__ uint4 pack8(const float* f){
  uint4 u;
  u.x = (unsigned int)f2b(f[0]) | ((unsigned int)f2b(f[1]) << 16);
  u.y = (unsigned int)f2b(f[2]) | ((unsigned int)f2b(f[3]) << 16);
  u.z = (unsigned int)f2b(f[4]) | ((unsigned int)f2b(f[5]) << 16);
  u.w = (unsigned int)f2b(f[6]) | ((unsigned int)f2b(f[7]) << 16);
  return u;
}

// ------------------------------------------------------------------
// embedding gather: x[row,:] = bf16(emb[idx(row),:])
__global__ __launch_bounds__(128) void embed_kernel(
    const float* __restrict__ emb, const int* __restrict__ xp, const int* __restrict__ xh,
    bf16* __restrict__ x, int NP, int N)
{
  int row = blockIdx.x; if (row >= N) return;
  int idx = (row < NP) ? xp[row] : xh[row - NP];
  float4 v = ((const float4*)(emb + (size_t)idx * DD))[threadIdx.x];
  ushort4 o; o.x = f2b(v.x); o.y = f2b(v.y); o.z = f2b(v.z); o.w = f2b(v.w);
  ((ushort4*)(x + (size_t)row * DD))[threadIdx.x] = o;
}

// ------------------------------------------------------------------
__global__ void mark_starts(const int* __restrict__ batch, int* __restrict__ starts, int n, int B)
{
  int i = blockIdx.x * blockDim.x + threadIdx.x; if (i >= n) return;
  int b = batch[i];
  if (i == 0) starts[0] = 0;
  else if (batch[i-1] != b) starts[b] = i;
  if (i == n-1) starts[B] = n;
}

__global__ __launch_bounds__(256) void compute_maxlen(
    const int* __restrict__ sp, const int* __restrict__ sh, int B, int* __restrict__ devL)
{
  __shared__ int red[256];
  int tid = threadIdx.x;
  int ml = 0;
  for (int b = tid; b < B; b += 256) ml = max(ml, sp[b+1]-sp[b]);
  red[tid] = ml; __syncthreads();
  for (int s = 128; s; s >>= 1){ if (tid < s) red[tid] = max(red[tid], red[tid+s]); __syncthreads(); }
  if (tid == 0) devL[0] = red[0];
  __syncthreads();
  ml = 0;
  for (int b = tid; b < B; b += 256) ml = max(ml, sh[b+1]-sh[b]);
  red[tid] = ml; __syncthreads();
  for (int s = 128; s; s >>= 1){ if (tid < s) red[tid] = max(red[tid], red[tid+s]); __syncthreads(); }
  if (tid == 0) devL[1] = red[0];
}

// ------------------------------------------------------------------
__global__ void edge_count(const int* __restrict__ ep, const int* __restrict__ eh,
                           int E2P, int E2H, int NP, int N, int* __restrict__ counts)
{
  int e = blockIdx.x * blockDim.x + threadIdx.x;
  int EALL = E2P + E2H + N;
  if (e >= EALL) return;
  int dst;
  if (e < E2P)            dst = ep[E2P + e];
  else if (e < E2P + E2H) dst = NP + eh[E2H + (e - E2P)];
  else                    dst = e - E2P - E2H;
  atomicAdd(&counts[dst], 1);
}

__global__ void edge_fill(const int* __restrict__ ep, const int* __restrict__ eh,
                          int E2P, int E2H, int NP, int N,
                          const int* __restrict__ off, int* __restrict__ cursor,
                          int* __restrict__ csr_src)
{
  int e = blockIdx.x * blockDim.x + threadIdx.x;
  int EALL = E2P + E2H + N;
  if (e >= EALL) return;
  int src, dst;
  if (e < E2P)            { src = ep[e];                 dst = ep[E2P + e]; }
  else if (e < E2P + E2H) { int j = e - E2P; src = NP + eh[j]; dst = NP + eh[E2H + j]; }
  else                    { src = dst = e - E2P - E2H; }
  int pos = atomicAdd(&cursor[dst], 1);
  csr_src[off[dst] + pos] = src;
}

__global__ __launch_bounds__(1024) void exscan(const int* __restrict__ in, int* __restrict__ out, int n)
{
  __shared__ int buf[1024];
  __shared__ int carry;
  int tid = threadIdx.x;
  if (tid == 0) carry = 0;
  __syncthreads();
  for (int base = 0; base < n; base += 1024){
    int x = (base + tid < n) ? in[base + tid] : 0;
    buf[tid] = x; __syncthreads();
    for (int off = 1; off < 1024; off <<= 1){
      int v = (tid >= off) ? buf[tid - off] : 0;
      __syncthreads();
      buf[tid] += v;
      __syncthreads();
    }
    if (base + tid < n) out[base + tid] = carry + buf[tid] - x;
    __syncthreads();
    if (tid == 0) carry += buf[1023];
    __syncthreads();
  }
  if (tid == 0) out[n] = carry;
}

// ------------------------------------------------------------------
// 64x64-tile transpose + f32->bf16: dst[n][k] = bf16(src[k][n]); both 512x512
__global__ __launch_bounds__(256) void transpose_w(const float* __restrict__ src, bf16* __restrict__ dst)
{
  __shared__ float t[64][65];
  int k0 = blockIdx.x * 64, n0 = blockIdx.y * 64;
  int tid = threadIdx.x;
  int r = tid >> 4, c4 = (tid & 15) * 4;
  #pragma unroll
  for (int p = 0; p < 4; p++){
    int row = r + p*16;
    float4 v = *(const float4*)(src + (size_t)(k0 + row) * DD + n0 + c4);
    t[c4+0][row] = v.x; t[c4+1][row] = v.y; t[c4+2][row] = v.z; t[c4+3][row] = v.w;
  }
  __syncthreads();
  #pragma unroll
  for (int p = 0; p < 4; p++){
    int row = r + p*16;  // n-within-tile
    ushort4 o;
    o.x = f2b(t[row][c4+0]); o.y = f2b(t[row][c4+1]);
    o.z = f2b(t[row][c4+2]); o.w = f2b(t[row][c4+3]);
    *(ushort4*)(dst + (size_t)(n0 + row) * DD + k0 + c4) = o;
  }
}

// ------------------------------------------------------------------
// MFMA bf16 GEMM: C[M,512] = A[M,512] @ W[512,512] (+bias)(+=C)(relu)
// WT is the pre-transposed bf16 weight: WT[n][k] = W[k][n].
// 128x128 tile, BK=64, 4 waves (2x2), 16x16x32 MFMA, XOR-swizzled LDS.
// flags: bit0 = accumulate into C, bit1 = relu
__global__ __launch_bounds__(256) void gemm_mfma(
    const bf16* __restrict__ A, const bf16* __restrict__ WT, const float* __restrict__ bias,
    bf16* __restrict__ C, int M, int flags)
{
  __shared__ __align__(16) bf16 Asub[128*64];
  __shared__ __align__(16) bf16 Bsub[128*64];
  int tid = threadIdx.x;
  int wave = tid >> 6, lane = tid & 63;
  int wr = wave >> 1, wc = wave & 1;
  int row0 = blockIdx.x * 128, col0 = blockIdx.y * 128;
  int l15 = lane & 15, l4 = lane >> 4;
  f32x4 acc[4][4];
  #pragma unroll
  for (int m = 0; m < 4; m++)
    #pragma unroll
    for (int n = 0; n < 4; n++)
      acc[m][n] = (f32x4){0.f, 0.f, 0.f, 0.f};

  for (int k0 = 0; k0 < DD; k0 += 64){
    #pragma unroll
    for (int p = 0; p < 2; p++){
      int chunk = tid + p*256;         // 512 chunks: 128 rows x 4 x 16B
      int r = chunk >> 2, cb = chunk & 3;
      uint4 av = *(const uint4*)(A  + (size_t)(row0 + r) * DD + k0 + cb*8);
      uint4 bv = *(const uint4*)(WT + (size_t)(col0 + r) * DD + k0 + cb*8);
      int off = r*128 + ((cb*16) ^ ((r&7)<<4));
      *(uint4*)((char*)Asub + off) = av;
      *(uint4*)((char*)Bsub + off) = bv;
    }
    __syncthreads();
    #pragma unroll
    for (int kk = 0; kk < 2; kk++){
      int colb = kk*64 + (l4<<4);
      short8v af[4], bfr[4];
      #pragma unroll
      for (int m = 0; m < 4; m++){
        int ar = wr*64 + m*16 + l15;
        af[m]  = *(const short8v*)((const char*)Asub + ar*128 + (colb ^ ((ar&7)<<4)));
        int br = wc*64 + m*16 + l15;
        bfr[m] = *(const short8v*)((const char*)Bsub + br*128 + (colb ^ ((br&7)<<4)));
      }
      #pragma unroll
      for (int m = 0; m < 4; m++)
        #pragma unroll
        for (int n = 0; n < 4; n++)
          acc[m][n] = __builtin_amdgcn_mfma_f32_16x16x32_bf16(af[m], bfr[n], acc[m][n], 0, 0, 0);
    }
    __syncthreads();
  }

  // epilogue: D col=lane&15, row=(lane>>4)*4+r  [verified m89 layout]
  #pragma unroll
  for (int m = 0; m < 4; m++){
    #pragma unroll
    for (int n = 0; n < 4; n++){
      int gc = col0 + wc*64 + n*16 + l15;
      float bv = bias ? bias[gc] : 0.f;
      #pragma unroll
      for (int r = 0; r < 4; r++){
        int gr = row0 + wr*64 + m*16 + l4*4 + r;
        if (gr < M){
          float v = acc[m][n][r] + bv;
          bf16* cp = C + (size_t)gr * DD + gc;
          if (flags & 1) v += b2f(*cp);
          if (flags & 2) v = fmaxf(v, 0.f);
          *cp = f2b(v);
        }
      }
    }
  }
}

// ------------------------------------------------------------------
// f32 tiled GEMM (small-M paths only: pad rows, classifier)
__global__ __launch_bounds__(256) void gemm64(
    const float* __restrict__ A, const float* __restrict__ W, const float* __restrict__ bias,
    float* __restrict__ C, int M, int Ncol, int flags)
{
  __shared__ float As[16][65];
  __shared__ float Bs[16][64];
  int tid = threadIdx.x;
  int tx = tid & 15, ty = tid >> 4;
  int row0 = blockIdx.x * 64, col0 = blockIdx.y * 64;
  float acc[4][4] = {};
  int lr = tid >> 2, lk = (tid & 3) * 4;
  int bk = tid >> 4, bn = (tid & 15) * 4;
  for (int k0 = 0; k0 < DD; k0 += 16){
    float a0 = 0.f, a1 = 0.f, a2 = 0.f, a3 = 0.f;
    int gr = row0 + lr;
    if (gr < M){
      float4 av = *(const float4*)(A + (size_t)gr * DD + k0 + lk);
      a0 = av.x; a1 = av.y; a2 = av.z; a3 = av.w;
    }
    As[lk+0][lr] = a0; As[lk+1][lr] = a1; As[lk+2][lr] = a2; As[lk+3][lr] = a3;
    *(float4*)&Bs[bk][bn] = *(const float4*)(W + (size_t)(k0 + bk) * Ncol + col0 + bn);
    __syncthreads();
    #pragma unroll
    for (int k = 0; k < 16; k++){
      float x0 = As[k][ty*4+0], x1 = As[k][ty*4+1], x2 = As[k][ty*4+2], x3 = As[k][ty*4+3];
      float y0 = Bs[k][tx*4+0], y1 = Bs[k][tx*4+1], y2 = Bs[k][tx*4+2], y3 = Bs[k][tx*4+3];
      acc[0][0] += x0*y0; acc[0][1] += x0*y1; acc[0][2] += x0*y2; acc[0][3] += x0*y3;
      acc[1][0] += x1*y0; acc[1][1] += x1*y1; acc[1][2] += x1*y2; acc[1][3] += x1*y3;
      acc[2][0] += x2*y0; acc[2][1] += x2*y1; acc[2][2] += x2*y2; acc[2][3] += x2*y3;
      acc[3][0] += x3*y0; acc[3][1] += x3*y1; acc[3][2] += x3*y2; acc[3][3] += x3*y3;
    }
    __syncthreads();
  }
  #pragma unroll
  for (int i = 0; i < 4; i++){
    int gr = row0 + ty*4 + i; if (gr >= M) continue;
    float r0 = acc[i][0], r1 = acc[i][1], r2 = acc[i][2], r3 = acc[i][3];
    if (bias){
      float4 bv = *(const float4*)(bias + col0 + tx*4);
      r0 += bv.x; r1 += bv.y; r2 += bv.z; r3 += bv.w;
    }
    float4* cp = (float4*)(C + (size_t)gr * Ncol + col0 + tx*4);
    if (flags & 1){
      float4 o = *cp;
      r0 += o.x; r1 += o.y; r2 += o.z; r3 += o.w;
    }
    if (flags & 2){
      r0 = fmaxf(r0, 0.f); r1 = fmaxf(r1, 0.f); r2 = fmaxf(r2, 0.f); r3 = fmaxf(r3, 0.f);
    }
    *cp = make_float4(r0, r1, r2, r3);
  }
}

// ------------------------------------------------------------------
__global__ __launch_bounds__(64) void gat_attn_coeff(
    const bf16* __restrict__ xw, const float* __restrict__ att_src, const float* __restrict__ att_dst,
    float* __restrict__ a_s, float* __restrict__ a_d, int N)
{
  int n = blockIdx.x; if (n >= N) return;
  int lane = threadIdx.x;
  float x[8];
  unpack8(*(const uint4*)(xw + (size_t)n * DD + lane * 8), x);
  const float4* sr = (const float4*)(att_src + lane * 8);
  const float4* dr = (const float4*)(att_dst + lane * 8);
  float4 s0 = sr[0], s1 = sr[1], d0 = dr[0], d1 = dr[1];
  float ps = x[0]*s0.x + x[1]*s0.y + x[2]*s0.z + x[3]*s0.w
           + x[4]*s1.x + x[5]*s1.y + x[6]*s1.z + x[7]*s1.w;
  float pd = x[0]*d0.x + x[1]*d0.y + x[2]*d0.z + x[3]*d0.w
           + x[4]*d1.x + x[5]*d1.y + x[6]*d1.z + x[7]*d1.w;
  for (int off = 1; off < 8; off <<= 1){ ps += __shfl_xor(ps, off); pd += __shfl_xor(pd, off); }
  if ((lane & 7) == 0){
    a_s[n*8 + (lane>>3)] = ps;
    a_d[n*8 + (lane>>3)] = pd;
  }
}

__global__ __launch_bounds__(64) void gat_aggregate(
    const bf16* __restrict__ xw, const float* __restrict__ a_s, const float* __restrict__ a_d,
    const int* __restrict__ csr_off, const int* __restrict__ csr_src,
    const float* __restrict__ bias, bf16* __restrict__ out, int N)
{
  int n = blockIdx.x; if (n >= N) return;
  int lane = threadIdx.x;
  int h = lane >> 3;
  int o0 = csr_off[n], deg = csr_off[n+1] - o0;
  float adh = a_d[n*8 + h];
  float mx = -3.4e38f;
  for (int e = 0; e < deg; e++){
    int s = csr_src[o0 + e];
    float v = a_s[s*8 + h] + adh;
    v = (v >= 0.f) ? v : SLOPE * v;
    mx = fmaxf(mx, v);
  }
  float den = 0.f;
  for (int e = 0; e < deg; e++){
    int s = csr_src[o0 + e];
    float v = a_s[s*8 + h] + adh;
    v = (v >= 0.f) ? v : SLOPE * v;
    den += __expf(v - mx);
  }
  float inv = 1.f / (den + 1e-16f);
  float A[8] = {};
  for (int e = 0; e < deg; e++){
    int s = csr_src[o0 + e];
    float v = a_s[s*8 + h] + adh;
    v = (v >= 0.f) ? v : SLOPE * v;
    float al = __expf(v - mx) * inv;
    float x[8];
    unpack8(*(const uint4*)(xw + (size_t)s * DD + lane * 8), x);
    #pragma unroll
    for (int j = 0; j < 8; j++) A[j] += al * x[j];
  }
  const float4* bq = (const float4*)(bias + lane * 8);
  float4 b0 = bq[0], b1 = bq[1];
  float r[8] = { A[0]+b0.x, A[1]+b0.y, A[2]+b0.z, A[3]+b0.w,
                 A[4]+b1.x, A[5]+b1.y, A[6]+b1.z, A[7]+b1.w };
  *(uint4*)(out + (size_t)n * DD + lane * 8) = pack8(r);
}

// ------------------------------------------------------------------
__global__ __launch_bounds__(256) void attn_kernel(
    const bf16* __restrict__ Q, const bf16* __restrict__ K, const bf16* __restrict__ V,
    const int* __restrict__ starts_p, const int* __restrict__ hbatch,
    bf16* __restrict__ phat, int NH)
{
  int i = blockIdx.x; if (i >= NH) return;
  int b = hbatch[i];
  int sp = starts_p[b], lp = starts_p[b+1] - sp;
  __shared__ float qs[DD];
  __shared__ float sc[384];
  __shared__ float red[256];
  int tid = threadIdx.x;
  ushort2 qv = ((const ushort2*)(Q + (size_t)i * DD))[tid];
  qs[tid*2] = b2f(qv.x); qs[tid*2+1] = b2f(qv.y);
  __syncthreads();
  int wid = tid >> 6, lane = tid & 63;
  const float scale = 0.044194173824159216f; // 1/sqrt(512)
  for (int m = wid; m < lp; m += 4){
    float kk[8];
    unpack8(*(const uint4*)(K + (size_t)(sp + m) * DD + lane * 8), kk);
    float4 q0 = ((const float4*)qs)[lane*2], q1 = ((const float4*)qs)[lane*2+1];
    float p = q0.x*kk[0] + q0.y*kk[1] + q0.z*kk[2] + q0.w*kk[3]
            + q1.x*kk[4] + q1.y*kk[5] + q1.z*kk[6] + q1.w*kk[7];
    for (int off = 32; off; off >>= 1) p += __shfl_xor(p, off);
    if (lane == 0) sc[m] = p * scale;
  }
  __syncthreads();
  float mx = -3.4e38f;
  for (int m = tid; m < lp; m += 256) mx = fmaxf(mx, sc[m]);
  red[tid] = mx; __syncthreads();
  for (int s = 128; s; s >>= 1){ if (tid < s) red[tid] = fmaxf(red[tid], red[tid+s]); __syncthreads(); }
  mx = red[0]; __syncthreads();
  float sm = 0.f;
  for (int m = tid; m < lp; m += 256){ float e = __expf(sc[m] - mx); sc[m] = e; sm += e; }
  red[tid] = sm; __syncthreads();
  for (int s = 128; s; s >>= 1){ if (tid < s) red[tid] += red[tid+s]; __syncthreads(); }
  float inv = 1.f / (red[0] + 1e-16f);
  float ax = 0.f, ay = 0.f;
  for (int m = 0; m < lp; m++){
    float a = sc[m] * inv;
    ushort2 vv = ((const ushort2*)(V + (size_t)(sp + m) * DD))[tid];
    ax += a * b2f(vv.x); ay += a * b2f(vv.y);
  }
  ushort2 o; o.x = f2b(ax); o.y = f2b(ay);
  ((ushort2*)(phat + (size_t)i * DD))[tid] = o;
}

__global__ __launch_bounds__(256) void vsum_kernel(
    const bf16* __restrict__ V, const int* __restrict__ sp_arr, const int* __restrict__ devL,
    float* __restrict__ padphat)
{
  int b = blockIdx.x, tid = threadIdx.x;
  int sp = sp_arr[b], lp = sp_arr[b+1] - sp;
  float ax = 0.f, ay = 0.f;
  for (int m = 0; m < lp; m++){
    ushort2 vv = ((const ushort2*)(V + (size_t)(sp + m) * DD))[tid];
    ax += b2f(vv.x); ay += b2f(vv.y);
  }
  float invLp = 1.f / (float)devL[0];
  ((float2*)(padphat + (size_t)b * DD))[tid] = make_float2(ax * invLp, ay * invLp);
}

__global__ void prod_kernel(const bf16* __restrict__ a, const bf16* __restrict__ b,
                            bf16* __restrict__ c, size_t n8)
{
  size_t i = (size_t)blockIdx.x * blockDim.x + threadIdx.x;
  if (i >= n8) return;
  float fa[8], fb[8], fc[8];
  unpack8(((const uint4*)a)[i], fa);
  unpack8(((const uint4*)b)[i], fb);
  #pragma unroll
  for (int j = 0; j < 8; j++) fc[j] = fa[j] * fb[j];
  ((uint4*)c)[i] = pack8(fc);
}

__global__ void wcomb_kernel(const float* __restrict__ w1, float* __restrict__ Wp, float* __restrict__ Wh)
{
  int i = blockIdx.x * blockDim.x + threadIdx.x;
  if (i >= DD*DD) return;
  float a = w1[i], b = w1[i + DD*DD], c = w1[i + 2*DD*DD];
  Wp[i] = a + c;
  Wh[i] = b - c;
}

__global__ __launch_bounds__(256) void pool_kernel(
    const bf16* __restrict__ cmp, const float* __restrict__ padcmp,
    const int* __restrict__ sh_arr, const int* __restrict__ devL,
    float* __restrict__ smax, float* __restrict__ smean)
{
  int b = blockIdx.x, tid = threadIdx.x;
  int sh = sh_arr[b], lh = sh_arr[b+1] - sh;
  int Lh = devL[1];
  float mxx = -3.4e38f, mxy = -3.4e38f, smx = 0.f, smy = 0.f;
  for (int r = 0; r < lh; r++){
    ushort2 v = ((const ushort2*)(cmp + (size_t)(sh + r) * DD))[tid];
    float vx = b2f(v.x), vy = b2f(v.y);
    mxx = fmaxf(mxx, vx); mxy = fmaxf(mxy, vy);
    smx += vx; smy += vy;
  }
  int npad = Lh - lh;
  if (npad > 0){
    float2 p = ((const float2*)(padcmp + (size_t)b * DD))[tid];
    mxx = fmaxf(mxx, p.x); mxy = fmaxf(mxy, p.y);
    smx += npad * p.x; smy += npad * p.y;
  }
  float invLh = 1.f / (float)Lh;
  ((float2*)(smax + (size_t)b * DD))[tid] = make_float2(mxx, mxy);
  ((float2*)(smean + (size_t)b * DD))[tid] = make_float2(smx * invLh, smy * invLh);
}

__global__ __launch_bounds__(64) void logits_kernel(
    const float* __restrict__ z1, const float* __restrict__ c2, const float* __restrict__ cb2,
    float* __restrict__ out, int B)
{
  int b = blockIdx.x; int lane = threadIdx.x;
  const float4* zr = (const float4*)(z1 + (size_t)b * DD);
  float4 z0 = zr[lane*2], z1v = zr[lane*2+1];
  float zz[8] = {z0.x, z0.y, z0.z, z0.w, z1v.x, z1v.y, z1v.z, z1v.w};
  float p0 = 0.f, p1 = 0.f, p2 = 0.f;
  #pragma unroll
  for (int j = 0; j < 8; j++){
    int k = lane*8 + j;
    p0 += zz[j] * c2[k*3 + 0];
    p1 += zz[j] * c2[k*3 + 1];
    p2 += zz[j] * c2[k*3 + 2];
  }
  for (int off = 32; off; off >>= 1){
    p0 += __shfl_xor(p0, off); p1 += __shfl_xor(p1, off); p2 += __shfl_xor(p2, off);
  }
  if (lane == 0){
    out[1 + b*3 + 0] = p0 + cb2[0];
    out[1 + b*3 + 1] = p1 + cb2[1];
    out[1 + b*3 + 2] = p2 + cb2[2];
  }
}

__global__ __launch_bounds__(256) void loss_kernel(
    const float* __restrict__ dout, const float* __restrict__ label, float* __restrict__ out0, int n)
{
  __shared__ float red[256];
  int tid = threadIdx.x;
  float s = 0.f;
  for (int i = tid; i < n; i += 256){
    float z = dout[1 + i], y = label[i];
    s += fmaxf(z, 0.f) - z*y + log1pf(expf(-fabsf(z)));
  }
  red[tid] = s; __syncthreads();
  for (int st = 128; st; st >>= 1){ if (tid < st) red[tid] += red[tid+st]; __syncthreads(); }
  if (tid == 0) out0[0] = red[0] / (float)n;
}

// ------------------------------------------------------------------
extern "C" void kernel_launch(void* const* d_in, const int* in_sizes, int n_in,
                              void* d_out, int out_size, void* d_ws, size_t ws_size,
                              hipStream_t stream)
{
  const float* emb   = (const float*)d_in[0];
  const float* Wgat  = (const float*)d_in[1];
  const float* att_s = (const float*)d_in[2];
  const float* att_d = (const float*)d_in[3];
  const float* gbias = (const float*)d_in[4];
  const float* Wq    = (const float*)d_in[5];
  const float* Wk    = (const float*)d_in[6];
  const float* Wv    = (const float*)d_in[7];
  const float* w1    = (const float*)d_in[8];
  const float* b1    = (const float*)d_in[9];
  const float* w2    = (const float*)d_in[10];
  const float* b2    = (const float*)d_in[11];
  const float* c1    = (const float*)d_in[12];
  const float* cb1   = (const float*)d_in[13];
  const float* c2    = (const float*)d_in[14];
  const float* cb2   = (const float*)d_in[15];
  const float* label = (const float*)d_in[16];
  const int* xp = (const int*)d_in[17];
  const int* xh = (const int*)d_in[18];
  const int* ep = (const int*)d_in[19];
  const int* eh = (const int*)d_in[20];
  const int* bp = (const int*)d_in[21];
  const int* bh = (const int*)d_in[22];

  const int NP  = in_sizes[17], NH = in_sizes[18];
  const int N   = NP + NH;
  const int E2P = in_sizes[19] / 2, E2H = in_sizes[20] / 2;
  const int EALL = E2P + E2H + N;
  const int B = in_sizes[16] / 3;

  char* wptr = (char*)d_ws;
  auto alloc = [&](size_t bytes) -> void* {
    void* p = (void*)wptr; wptr += (bytes + 255) & ~(size_t)255; return p;
  };
  bf16* bufX = (bf16*)alloc((size_t)N  * DD * 2);  // node features / enc
  bf16* bufY = (bf16*)alloc((size_t)N  * DD * 2);  // xw ; later K ; later hidden
  bf16* bufV = (bf16*)alloc((size_t)NP * DD * 2);  // V ; later cmp
  bf16* bufQ = (bf16*)alloc((size_t)NH * DD * 2);  // Q ; later p_hat*h
  bf16* bufP = (bf16*)alloc((size_t)NH * DD * 2);  // p_hat
  float* a_s  = (float*)alloc((size_t)N * 8 * 4);
  float* a_d  = (float*)alloc((size_t)N * 8 * 4);
  int* counts   = (int*)alloc((size_t)N * 4);
  int* csr_off  = (int*)alloc((size_t)(N + 1) * 4);
  int* cursor   = (int*)alloc((size_t)N * 4);
  int* csr_src  = (int*)alloc((size_t)EALL * 4);
  int* starts_p = (int*)alloc((size_t)(B + 1) * 4);
  int* starts_h = (int*)alloc((size_t)(B + 1) * 4);
  int* devL     = (int*)alloc(64);
  float* padphat = (float*)alloc((size_t)B * DD * 4);
  float* padhid  = (float*)alloc((size_t)B * DD * 4);
  float* padcmp  = (float*)alloc((size_t)B * DD * 4);
  float* smax  = (float*)alloc((size_t)B * DD * 4);
  float* smean = (float*)alloc((size_t)B * DD * 4);
  float* z1    = (float*)alloc((size_t)B * DD * 4);
  float* Wpc   = (float*)alloc((size_t)DD * DD * 4);
  float* Whc   = (float*)alloc((size_t)DD * DD * 4);
  // bf16 transposed weights for MFMA path
  bf16* WT_gat = (bf16*)alloc((size_t)DD * DD * 2);
  bf16* WT_q   = (bf16*)alloc((size_t)DD * DD * 2);
  bf16* WT_k   = (bf16*)alloc((size_t)DD * DD * 2);
  bf16* WT_v   = (bf16*)alloc((size_t)DD * DD * 2);
  bf16* WT_pc  = (bf16*)alloc((size_t)DD * DD * 2);
  bf16* WT_hc  = (bf16*)alloc((size_t)DD * DD * 2);
  bf16* WT_1d  = (bf16*)alloc((size_t)DD * DD * 2);
  bf16* WT_2   = (bf16*)alloc((size_t)DD * DD * 2);

  hipMemsetAsync(counts, 0, (size_t)N * 4, stream);
  hipMemsetAsync(cursor, 0, (size_t)N * 4, stream);

  embed_kernel<<<N, 128, 0, stream>>>(emb, xp, xh, bufX, NP, N);
  mark_starts<<<(NP + 255)/256, 256, 0, stream>>>(bp, starts_p, NP, B);
  mark_starts<<<(NH + 255)/256, 256, 0, stream>>>(bh, starts_h, NH, B);
  compute_maxlen<<<1, 256, 0, stream>>>(starts_p, starts_h, B, devL);
  edge_count<<<(EALL + 255)/256, 256, 0, stream>>>(ep, eh, E2P, E2H, NP, N, counts);
  exscan<<<1, 1024, 0, stream>>>(counts, csr_off, N);
  edge_fill<<<(EALL + 255)/256, 256, 0, stream>>>(ep, eh, E2P, E2H, NP, N, csr_off, cursor, csr_src);
  wcomb_kernel<<<(DD*DD + 255)/256, 256, 0, stream>>>(w1, Wpc, Whc);

  dim3 tg(8, 8);
  transpose_w<<<tg, 256, 0, stream>>>(Wgat, WT_gat);
  transpose_w<<<tg, 256, 0, stream>>>(Wq,   WT_q);
  transpose_w<<<tg, 256, 0, stream>>>(Wk,   WT_k);
  transpose_w<<<tg, 256, 0, stream>>>(Wv,   WT_v);
  transpose_w<<<tg, 256, 0, stream>>>(Wpc,  WT_pc);
  transpose_w<<<tg, 256, 0, stream>>>(Whc,  WT_hc);
  transpose_w<<<tg, 256, 0, stream>>>(w1 + (size_t)3*DD*DD, WT_1d);
  transpose_w<<<tg, 256, 0, stream>>>(w2,   WT_2);

  auto gemmM = [&](const bf16* A, const bf16* WT, const float* bias, bf16* Cv, int M, int flags){
    dim3 g((unsigned)((M + 127)/128), 4);
    gemm_mfma<<<g, 256, 0, stream>>>(A, WT, bias, Cv, M, flags);
  };
  auto gemmF = [&](const float* A, const float* Wm, const float* bias, float* Cv, int M, int flags){
    dim3 g((unsigned)((M + 63)/64), DD/64);
    gemm64<<<g, 256, 0, stream>>>(A, Wm, bias, Cv, M, DD, flags);
  };

  // 3 shared-weight GAT layers on the combined graph
  for (int l = 0; l < 3; l++){
    gemmM(bufX, WT_gat, nullptr, bufY, N, 0);
    gat_attn_coeff<<<N, 64, 0, stream>>>(bufY, att_s, att_d, a_s, a_d, N);
    gat_aggregate<<<N, 64, 0, stream>>>(bufY, a_s, a_d, csr_off, csr_src, gbias, bufX, N);
  }

  const bf16* h_enc = bufX + (size_t)NP * DD;
  gemmM(h_enc, WT_q, nullptr, bufQ, NH, 0);
  gemmM(bufX,  WT_k, nullptr, bufY, NP, 0);   // K
  gemmM(bufX,  WT_v, nullptr, bufV, NP, 0);   // V
  attn_kernel<<<NH, 256, 0, stream>>>(bufQ, bufY, bufV, starts_p, bh, bufP, NH);
  vsum_kernel<<<B, 256, 0, stream>>>(bufV, starts_p, devL, padphat);

  size_t n8 = (size_t)NH * (DD/8);
  prod_kernel<<<(unsigned)((n8 + 255)/256), 256, 0, stream>>>(bufP, h_enc, bufQ, n8);

  bf16* hid = bufY;                        // K is dead
  gemmM(bufP, WT_pc, b1, hid, NH, 0);
  gemmM(h_enc, WT_hc, nullptr, hid, NH, 1);
  gemmM(bufQ, WT_1d, nullptr, hid, NH, 1 | 2);  // + relu
  bf16* cmp = bufV;                        // V is dead
  gemmM(hid, WT_2, b2, cmp, NH, 0);

  gemmF(padphat, Wpc, b1, padhid, B, 2);   // pad rows: feat = [p,0,p,0]
  gemmF(padhid, w2, b2, padcmp, B, 0);

  pool_kernel<<<B, 256, 0, stream>>>(cmp, padcmp, starts_h, devL, smax, smean);

  gemmF(smax,  c1,                 cb1,     z1, B, 0);
  gemmF(smean, c1 + (size_t)DD*DD, nullptr, z1, B, 1 | 2);
  logits_kernel<<<B, 64, 0, stream>>>(z1, c2, cb2, (float*)d_out, B);
  loss_kernel<<<1, 256, 0, stream>>>((float*)d_out, label, (float*)d_out, B * 3);
}

// Round 6
// 1941.561 us; speedup vs baseline: 2.5578x; 1.1726x over previous
//
#include <hip/hip_runtime.h>
#include <cstdint>
#include <cstddef>

#define DD 512
#define SLOPE 0.2f

typedef unsigned short bf16;
typedef __attribute__((ext_vector_type(8))) short short8v;  // 8 bf16 (4 VGPRs)
typedef __attribute__((ext_vector_type(4))) float f32x4;

__device__ __forceinline__ float b2f(unsigned short u){
  union { float f; unsigned int i; } v; v.i = ((unsigned int)u) << 16; return v.f;
}
__device__ __forceinline__ unsigned short f2b(float f){
  union { float f; unsigned int i; } v; v.f = f;
  unsigned int r = v.i + 0x7FFFu + ((v.i >> 16) & 1u);
  return (unsigned short)(r >> 16);
}
__device__ __forceinline__ void unpack8(uint4 u, float* f){
  f[0]=b2f((unsigned short)(u.x & 0xFFFFu)); f[1]=b2f((unsigned short)(u.x >> 16));
  f[2]=b2f((unsigned short)(u.y & 0xFFFFu)); f[3]=b2f((unsigned short)(u.y >> 16));
  f[4]=b2f((unsigned short)(u.z & 0xFFFFu)); f[5]=b2f((unsigned short)(u.z >> 16));
  f[6]=b2f((unsigned short)(u.w & 0xFFFFu)); f[7]=b2f((unsigned short)(u.w >> 16));
}
__device__ __forceinline__ uint4 pack8(const float* f){
  uint4 u;
  u.x = (unsigned int)f2b(f[0]) | ((unsigned int)f2b(f[1]) << 16);
  u.y = (unsigned int)f2b(f[2]) | ((unsigned int)f2b(f[3]) << 16);
  u.z = (unsigned int)f2b(f[4]) | ((unsigned int)f2b(f[5]) << 16);
  u.w = (unsigned int)f2b(f[6]) | ((unsigned int)f2b(f[7]) << 16);
  return u;
}

// ------------------------------------------------------------------
__global__ __launch_bounds__(128) void embed_kernel(
    const float* __restrict__ emb, const int* __restrict__ xp, const int* __restrict__ xh,
    bf16* __restrict__ x, int NP, int N)
{
  int row = blockIdx.x; if (row >= N) return;
  int idx = (row < NP) ? xp[row] : xh[row - NP];
  float4 v = ((const float4*)(emb + (size_t)idx * DD))[threadIdx.x];
  ushort4 o; o.x = f2b(v.x); o.y = f2b(v.y); o.z = f2b(v.z); o.w = f2b(v.w);
  ((ushort4*)(x + (size_t)row * DD))[threadIdx.x] = o;
}

// ------------------------------------------------------------------
__global__ void mark_starts(const int* __restrict__ batch, int* __restrict__ starts, int n, int B)
{
  int i = blockIdx.x * blockDim.x + threadIdx.x; if (i >= n) return;
  int b = batch[i];
  if (i == 0) starts[0] = 0;
  else if (batch[i-1] != b) starts[b] = i;
  if (i == n-1) starts[B] = n;
}

__global__ __launch_bounds__(256) void compute_maxlen(
    const int* __restrict__ sp, const int* __restrict__ sh, int B, int* __restrict__ devL)
{
  __shared__ int red[256];
  int tid = threadIdx.x;
  int ml = 0;
  for (int b = tid; b < B; b += 256) ml = max(ml, sp[b+1]-sp[b]);
  red[tid] = ml; __syncthreads();
  for (int s = 128; s; s >>= 1){ if (tid < s) red[tid] = max(red[tid], red[tid+s]); __syncthreads(); }
  if (tid == 0) devL[0] = red[0];
  __syncthreads();
  ml = 0;
  for (int b = tid; b < B; b += 256) ml = max(ml, sh[b+1]-sh[b]);
  red[tid] = ml; __syncthreads();
  for (int s = 128; s; s >>= 1){ if (tid < s) red[tid] = max(red[tid], red[tid+s]); __syncthreads(); }
  if (tid == 0) devL[1] = red[0];
}

// ------------------------------------------------------------------
__global__ void edge_count(const int* __restrict__ ep, const int* __restrict__ eh,
                           int E2P, int E2H, int NP, int N, int* __restrict__ counts)
{
  int e = blockIdx.x * blockDim.x + threadIdx.x;
  int EALL = E2P + E2H + N;
  if (e >= EALL) return;
  int dst;
  if (e < E2P)            dst = ep[E2P + e];
  else if (e < E2P + E2H) dst = NP + eh[E2H + (e - E2P)];
  else                    dst = e - E2P - E2H;
  atomicAdd(&counts[dst], 1);
}

__global__ void edge_fill(const int* __restrict__ ep, const int* __restrict__ eh,
                          int E2P, int E2H, int NP, int N,
                          const int* __restrict__ off, int* __restrict__ cursor,
                          int* __restrict__ csr_src)
{
  int e = blockIdx.x * blockDim.x + threadIdx.x;
  int EALL = E2P + E2H + N;
  if (e >= EALL) return;
  int src, dst;
  if (e < E2P)            { src = ep[e];                 dst = ep[E2P + e]; }
  else if (e < E2P + E2H) { int j = e - E2P; src = NP + eh[j]; dst = NP + eh[E2H + j]; }
  else                    { src = dst = e - E2P - E2H; }
  int pos = atomicAdd(&cursor[dst], 1);
  csr_src[off[dst] + pos] = src;
}

__global__ __launch_bounds__(1024) void exscan(const int* __restrict__ in, int* __restrict__ out, int n)
{
  __shared__ int buf[1024];
  __shared__ int carry;
  int tid = threadIdx.x;
  if (tid == 0) carry = 0;
  __syncthreads();
  for (int base = 0; base < n; base += 1024){
    int x = (base + tid < n) ? in[base + tid] : 0;
    buf[tid] = x; __syncthreads();
    for (int off = 1; off < 1024; off <<= 1){
      int v = (tid >= off) ? buf[tid - off] : 0;
      __syncthreads();
      buf[tid] += v;
      __syncthreads();
    }
    if (base + tid < n) out[base + tid] = carry + buf[tid] - x;
    __syncthreads();
    if (tid == 0) carry += buf[1023];
    __syncthreads();
  }
  if (tid == 0) out[n] = carry;
}

// ------------------------------------------------------------------
// 64x64-tile transpose + f32->bf16: dst[n][k] = bf16(src[k][n]); both 512x512
__global__ __launch_bounds__(256) void transpose_w(const float* __restrict__ src, bf16* __restrict__ dst)
{
  __shared__ float t[64][65];
  int k0 = blockIdx.x * 64, n0 = blockIdx.y * 64;
  int tid = threadIdx.x;
  int r = tid >> 4, c4 = (tid & 15) * 4;
  #pragma unroll
  for (int p = 0; p < 4; p++){
    int row = r + p*16;
    float4 v = *(const float4*)(src + (size_t)(k0 + row) * DD + n0 + c4);
    t[c4+0][row] = v.x; t[c4+1][row] = v.y; t[c4+2][row] = v.z; t[c4+3][row] = v.w;
  }
  __syncthreads();
  #pragma unroll
  for (int p = 0; p < 4; p++){
    int row = r + p*16;  // n-within-tile
    ushort4 o;
    o.x = f2b(t[row][c4+0]); o.y = f2b(t[row][c4+1]);
    o.z = f2b(t[row][c4+2]); o.w = f2b(t[row][c4+3]);
    *(ushort4*)(dst + (size_t)(n0 + row) * DD + k0 + c4) = o;
  }
}

// bf16 [NP][512] -> bf16 [512][NPpad] transpose (Vt for PV MFMA)
__global__ __launch_bounds__(256) void transpose_v(
    const bf16* __restrict__ V, bf16* __restrict__ Vt, int NP, int NPpad)
{
  __shared__ bf16 t[64][72];
  int r0 = blockIdx.x * 64, c0 = blockIdx.y * 64;
  int tid = threadIdx.x;
  int row = tid >> 2, cc = (tid & 3) * 16;
  uint4 v0 = {0,0,0,0}, v1 = {0,0,0,0};
  if (r0 + row < NP){
    v0 = *(const uint4*)(V + (size_t)(r0+row) * DD + c0 + cc);
    v1 = *(const uint4*)(V + (size_t)(r0+row) * DD + c0 + cc + 8);
  }
  *(uint4*)&t[row][cc]   = v0;
  *(uint4*)&t[row][cc+8] = v1;
  __syncthreads();
  int col = tid >> 2, rr = (tid & 3) * 16;
  ushort o[16];
  #pragma unroll
  for (int j = 0; j < 16; j++) o[j] = t[rr + j][col];
  *(uint4*)(Vt + (size_t)(c0+col) * NPpad + r0 + rr)     = *(uint4*)&o[0];
  *(uint4*)(Vt + (size_t)(c0+col) * NPpad + r0 + rr + 8) = *(uint4*)&o[8];
}

// ------------------------------------------------------------------
// MFMA bf16 GEMM: C[M,512] = A[M,512] @ W[512,512] (+bias)(+=C)(relu)
__global__ __launch_bounds__(256) void gemm_mfma(
    const bf16* __restrict__ A, const bf16* __restrict__ WT, const float* __restrict__ bias,
    bf16* __restrict__ C, int M, int flags)
{
  __shared__ __align__(16) bf16 Asub[128*64];
  __shared__ __align__(16) bf16 Bsub[128*64];
  int tid = threadIdx.x;
  int wave = tid >> 6, lane = tid & 63;
  int wr = wave >> 1, wc = wave & 1;
  int row0 = blockIdx.x * 128, col0 = blockIdx.y * 128;
  int l15 = lane & 15, l4 = lane >> 4;
  f32x4 acc[4][4];
  #pragma unroll
  for (int m = 0; m < 4; m++)
    #pragma unroll
    for (int n = 0; n < 4; n++)
      acc[m][n] = (f32x4){0.f, 0.f, 0.f, 0.f};

  for (int k0 = 0; k0 < DD; k0 += 64){
    #pragma unroll
    for (int p = 0; p < 2; p++){
      int chunk = tid + p*256;
      int r = chunk >> 2, cb = chunk & 3;
      uint4 av = *(const uint4*)(A  + (size_t)(row0 + r) * DD + k0 + cb*8);
      uint4 bv = *(const uint4*)(WT + (size_t)(col0 + r) * DD + k0 + cb*8);
      int off = r*128 + ((cb*16) ^ ((r&7)<<4));
      *(uint4*)((char*)Asub + off) = av;
      *(uint4*)((char*)Bsub + off) = bv;
    }
    __syncthreads();
    #pragma unroll
    for (int kk = 0; kk < 2; kk++){
      int colb = kk*64 + (l4<<4);
      short8v af[4], bfr[4];
      #pragma unroll
      for (int m = 0; m < 4; m++){
        int ar = wr*64 + m*16 + l15;
        af[m]  = *(const short8v*)((const char*)Asub + ar*128 + (colb ^ ((ar&7)<<4)));
        int br = wc*64 + m*16 + l15;
        bfr[m] = *(const short8v*)((const char*)Bsub + br*128 + (colb ^ ((br&7)<<4)));
      }
      #pragma unroll
      for (int m = 0; m < 4; m++)
        #pragma unroll
        for (int n = 0; n < 4; n++)
          acc[m][n] = __builtin_amdgcn_mfma_f32_16x16x32_bf16(af[m], bfr[n], acc[m][n], 0, 0, 0);
    }
    __syncthreads();
  }

  #pragma unroll
  for (int m = 0; m < 4; m++){
    #pragma unroll
    for (int n = 0; n < 4; n++){
      int gc = col0 + wc*64 + n*16 + l15;
      float bv = bias ? bias[gc] : 0.f;
      #pragma unroll
      for (int r = 0; r < 4; r++){
        int gr = row0 + wr*64 + m*16 + l4*4 + r;
        if (gr < M){
          float v = acc[m][n][r] + bv;
          bf16* cp = C + (size_t)gr * DD + gc;
          if (flags & 1) v += b2f(*cp);
          if (flags & 2) v = fmaxf(v, 0.f);
          *cp = f2b(v);
        }
      }
    }
  }
}

// ------------------------------------------------------------------
// scores S[sh+r][c] = Q[sh+r,:] . K[sp+c,:]  (per-graph 64x64 tiles)
__global__ __launch_bounds__(256) void score_mfma(
    const bf16* __restrict__ Q, const bf16* __restrict__ K,
    const int* __restrict__ sp_arr, const int* __restrict__ sh_arr,
    float* __restrict__ S, int NH, int NP)
{
  int b = blockIdx.x;
  int sh = sh_arr[b], lh = sh_arr[b+1] - sh;
  int sp = sp_arr[b], lp = sp_arr[b+1] - sp;
  int qt = blockIdx.y * 64, kt = blockIdx.z * 64;
  if (qt >= lh || kt >= lp) return;
  int tid = threadIdx.x, wave = tid >> 6, lane = tid & 63;
  int wr = (wave >> 1) * 32, wc = (wave & 1) * 32;
  int l15 = lane & 15, l4 = lane >> 4;
  f32x4 acc[2][2];
  #pragma unroll
  for (int m = 0; m < 2; m++)
    #pragma unroll
    for (int n = 0; n < 2; n++)
      acc[m][n] = (f32x4){0.f,0.f,0.f,0.f};
  int ar[2], br[2];
  #pragma unroll
  for (int m = 0; m < 2; m++) ar[m] = min(sh + qt + wr + m*16 + l15, NH-1);
  #pragma unroll
  for (int n = 0; n < 2; n++) br[n] = min(sp + kt + wc + n*16 + l15, NP-1);
  for (int k0 = 0; k0 < DD; k0 += 32){
    short8v af[2], bv[2];
    #pragma unroll
    for (int m = 0; m < 2; m++) af[m] = *(const short8v*)(Q + (size_t)ar[m]*DD + k0 + l4*8);
    #pragma unroll
    for (int n = 0; n < 2; n++) bv[n] = *(const short8v*)(K + (size_t)br[n]*DD + k0 + l4*8);
    #pragma unroll
    for (int m = 0; m < 2; m++)
      #pragma unroll
      for (int n = 0; n < 2; n++)
        acc[m][n] = __builtin_amdgcn_mfma_f32_16x16x32_bf16(af[m], bv[n], acc[m][n], 0, 0, 0);
  }
  #pragma unroll
  for (int m = 0; m < 2; m++)
    #pragma unroll
    for (int n = 0; n < 2; n++)
      #pragma unroll
      for (int i = 0; i < 4; i++){
        int rr = qt + wr + m*16 + l4*4 + i;
        int cc = kt + wc + n*16 + l15;
        if (rr < lh && cc < lp) S[(size_t)(sh+rr)*384 + cc] = acc[m][n][i];
      }
}

// masked softmax over S rows -> P bf16, shifted by d = sp&7 (stride 416)
__global__ __launch_bounds__(256) void softmax_rows(
    const float* __restrict__ S, bf16* __restrict__ P,
    const int* __restrict__ sp_arr, const int* __restrict__ hbatch, int NH)
{
  __shared__ float sm[4][384];
  int w = threadIdx.x >> 6, lane = threadIdx.x & 63;
  int i = blockIdx.x * 4 + w; if (i >= NH) return;
  int b = hbatch[i];
  int sp = sp_arr[b], lp = sp_arr[b+1] - sp;
  int d = sp & 7;
  const float scale = 0.044194173824159216f; // 1/sqrt(512)
  float e[6]; float mx = -3.4e38f;
  #pragma unroll
  for (int j = 0; j < 6; j++){
    int c = j*64 + lane;
    float v = (c < lp) ? S[(size_t)i*384 + c] * scale : -1e30f;
    e[j] = v; mx = fmaxf(mx, v);
  }
  for (int off = 32; off; off >>= 1) mx = fmaxf(mx, __shfl_xor(mx, off));
  float sum = 0.f;
  #pragma unroll
  for (int j = 0; j < 6; j++){ float x = __expf(e[j] - mx); e[j] = x; sum += x; }
  for (int off = 32; off; off >>= 1) sum += __shfl_xor(sum, off);
  float inv = 1.f / sum;
  #pragma unroll
  for (int j = 0; j < 6; j++) sm[w][j*64 + lane] = e[j];
  #pragma unroll
  for (int j = 0; j < 7; j++){
    int o = j*64 + lane;
    if (o < 416){
      int c = o - d;
      float val = (c >= 0 && c < lp) ? sm[w][c] * inv : 0.f;
      P[(size_t)i*416 + o] = f2b(val);
    }
  }
}

// p_hat[sh+r][col] = sum_k P[sh+r][k] * Vt[col][jp0+k]
__global__ __launch_bounds__(256) void pv_mfma(
    const bf16* __restrict__ P, const bf16* __restrict__ Vt,
    const int* __restrict__ sp_arr, const int* __restrict__ sh_arr,
    bf16* __restrict__ out, int NH, int NPpad)
{
  int b = blockIdx.x;
  int sh = sh_arr[b], lh = sh_arr[b+1] - sh;
  int sp = sp_arr[b], lp = sp_arr[b+1] - sp;
  int qt = blockIdx.y * 64;
  if (qt >= lh) return;
  int ct = blockIdx.z * 128;
  int d = sp & 7, jp0 = sp - d;
  int tid = threadIdx.x, wave = tid >> 6, lane = tid & 63;
  int wr = (wave >> 1) * 32, wc = (wave & 1) * 64;
  int l15 = lane & 15, l4 = lane >> 4;
  f32x4 acc[2][4];
  #pragma unroll
  for (int m = 0; m < 2; m++)
    #pragma unroll
    for (int n = 0; n < 4; n++)
      acc[m][n] = (f32x4){0.f,0.f,0.f,0.f};
  int ar[2];
  #pragma unroll
  for (int m = 0; m < 2; m++) ar[m] = min(sh + qt + wr + m*16 + l15, NH-1);
  int kmax = (lp + d + 31) & ~31;
  for (int k0 = 0; k0 < kmax; k0 += 32){
    short8v af[2], bv[4];
    #pragma unroll
    for (int m = 0; m < 2; m++) af[m] = *(const short8v*)(P + (size_t)ar[m]*416 + k0 + l4*8);
    #pragma unroll
    for (int n = 0; n < 4; n++){
      int vc = ct + wc + n*16 + l15;
      bv[n] = *(const short8v*)(Vt + (size_t)vc*NPpad + jp0 + k0 + l4*8);
    }
    #pragma unroll
    for (int m = 0; m < 2; m++)
      #pragma unroll
      for (int n = 0; n < 4; n++)
        acc[m][n] = __builtin_amdgcn_mfma_f32_16x16x32_bf16(af[m], bv[n], acc[m][n], 0, 0, 0);
  }
  #pragma unroll
  for (int m = 0; m < 2; m++)
    #pragma unroll
    for (int n = 0; n < 4; n++)
      #pragma unroll
      for (int i = 0; i < 4; i++){
        int rr = qt + wr + m*16 + l4*4 + i;
        int cc = ct + wc + n*16 + l15;
        if (rr < lh) out[(size_t)(sh+rr)*DD + cc] = f2b(acc[m][n][i]);
      }
}

// ------------------------------------------------------------------
// f32 tiled GEMM (small-M paths only: pad rows, classifier)
__global__ __launch_bounds__(256) void gemm64(
    const float* __restrict__ A, const float* __restrict__ W, const float* __restrict__ bias,
    float* __restrict__ C, int M, int Ncol, int flags)
{
  __shared__ float As[16][65];
  __shared__ float Bs[16][64];
  int tid = threadIdx.x;
  int tx = tid & 15, ty = tid >> 4;
  int row0 = blockIdx.x * 64, col0 = blockIdx.y * 64;
  float acc[4][4] = {};
  int lr = tid >> 2, lk = (tid & 3) * 4;
  int bk = tid >> 4, bn = (tid & 15) * 4;
  for (int k0 = 0; k0 < DD; k0 += 16){
    float a0 = 0.f, a1 = 0.f, a2 = 0.f, a3 = 0.f;
    int gr = row0 + lr;
    if (gr < M){
      float4 av = *(const float4*)(A + (size_t)gr * DD + k0 + lk);
      a0 = av.x; a1 = av.y; a2 = av.z; a3 = av.w;
    }
    As[lk+0][lr] = a0; As[lk+1][lr] = a1; As[lk+2][lr] = a2; As[lk+3][lr] = a3;
    *(float4*)&Bs[bk][bn] = *(const float4*)(W + (size_t)(k0 + bk) * Ncol + col0 + bn);
    __syncthreads();
    #pragma unroll
    for (int k = 0; k < 16; k++){
      float x0 = As[k][ty*4+0], x1 = As[k][ty*4+1], x2 = As[k][ty*4+2], x3 = As[k][ty*4+3];
      float y0 = Bs[k][tx*4+0], y1 = Bs[k][tx*4+1], y2 = Bs[k][tx*4+2], y3 = Bs[k][tx*4+3];
      acc[0][0] += x0*y0; acc[0][1] += x0*y1; acc[0][2] += x0*y2; acc[0][3] += x0*y3;
      acc[1][0] += x1*y0; acc[1][1] += x1*y1; acc[1][2] += x1*y2; acc[1][3] += x1*y3;
      acc[2][0] += x2*y0; acc[2][1] += x2*y1; acc[2][2] += x2*y2; acc[2][3] += x2*y3;
      acc[3][0] += x3*y0; acc[3][1] += x3*y1; acc[3][2] += x3*y2; acc[3][3] += x3*y3;
    }
    __syncthreads();
  }
  #pragma unroll
  for (int i = 0; i < 4; i++){
    int gr = row0 + ty*4 + i; if (gr >= M) continue;
    float r0 = acc[i][0], r1 = acc[i][1], r2 = acc[i][2], r3 = acc[i][3];
    if (bias){
      float4 bv = *(const float4*)(bias + col0 + tx*4);
      r0 += bv.x; r1 += bv.y; r2 += bv.z; r3 += bv.w;
    }
    float4* cp = (float4*)(C + (size_t)gr * Ncol + col0 + tx*4);
    if (flags & 1){
      float4 o = *cp;
      r0 += o.x; r1 += o.y; r2 += o.z; r3 += o.w;
    }
    if (flags & 2){
      r0 = fmaxf(r0, 0.f); r1 = fmaxf(r1, 0.f); r2 = fmaxf(r2, 0.f); r3 = fmaxf(r3, 0.f);
    }
    *cp = make_float4(r0, r1, r2, r3);
  }
}

// ------------------------------------------------------------------
__global__ __launch_bounds__(64) void gat_attn_coeff(
    const bf16* __restrict__ xw, const float* __restrict__ att_src, const float* __restrict__ att_dst,
    float* __restrict__ a_s, float* __restrict__ a_d, int N)
{
  int n = blockIdx.x; if (n >= N) return;
  int lane = threadIdx.x;
  float x[8];
  unpack8(*(const uint4*)(xw + (size_t)n * DD + lane * 8), x);
  const float4* sr = (const float4*)(att_src + lane * 8);
  const float4* dr = (const float4*)(att_dst + lane * 8);
  float4 s0 = sr[0], s1 = sr[1], d0 = dr[0], d1 = dr[1];
  float ps = x[0]*s0.x + x[1]*s0.y + x[2]*s0.z + x[3]*s0.w
           + x[4]*s1.x + x[5]*s1.y + x[6]*s1.z + x[7]*s1.w;
  float pd = x[0]*d0.x + x[1]*d0.y + x[2]*d0.z + x[3]*d0.w
           + x[4]*d1.x + x[5]*d1.y + x[6]*d1.z + x[7]*d1.w;
  for (int off = 1; off < 8; off <<= 1){ ps += __shfl_xor(ps, off); pd += __shfl_xor(pd, off); }
  if ((lane & 7) == 0){
    a_s[n*8 + (lane>>3)] = ps;
    a_d[n*8 + (lane>>3)] = pd;
  }
}

__global__ __launch_bounds__(64) void gat_aggregate(
    const bf16* __restrict__ xw, const float* __restrict__ a_s, const float* __restrict__ a_d,
    const int* __restrict__ csr_off, const int* __restrict__ csr_src,
    const float* __restrict__ bias, bf16* __restrict__ out, int N)
{
  int n = blockIdx.x; if (n >= N) return;
  int lane = threadIdx.x;
  int h = lane >> 3;
  int o0 = csr_off[n], deg = csr_off[n+1] - o0;
  float adh = a_d[n*8 + h];
  float mx = -3.4e38f;
  for (int e = 0; e < deg; e++){
    int s = csr_src[o0 + e];
    float v = a_s[s*8 + h] + adh;
    v = (v >= 0.f) ? v : SLOPE * v;
    mx = fmaxf(mx, v);
  }
  float den = 0.f;
  for (int e = 0; e < deg; e++){
    int s = csr_src[o0 + e];
    float v = a_s[s*8 + h] + adh;
    v = (v >= 0.f) ? v : SLOPE * v;
    den += __expf(v - mx);
  }
  float inv = 1.f / (den + 1e-16f);
  float A[8] = {};
  for (int e = 0; e < deg; e++){
    int s = csr_src[o0 + e];
    float v = a_s[s*8 + h] + adh;
    v = (v >= 0.f) ? v : SLOPE * v;
    float al = __expf(v - mx) * inv;
    float x[8];
    unpack8(*(const uint4*)(xw + (size_t)s * DD + lane * 8), x);
    #pragma unroll
    for (int j = 0; j < 8; j++) A[j] += al * x[j];
  }
  const float4* bq = (const float4*)(bias + lane * 8);
  float4 b0 = bq[0], b1 = bq[1];
  float r[8] = { A[0]+b0.x, A[1]+b0.y, A[2]+b0.z, A[3]+b0.w,
                 A[4]+b1.x, A[5]+b1.y, A[6]+b1.z, A[7]+b1.w };
  *(uint4*)(out + (size_t)n * DD + lane * 8) = pack8(r);
}

// ------------------------------------------------------------------
__global__ __launch_bounds__(256) void vsum_kernel(
    const bf16* __restrict__ V, const int* __restrict__ sp_arr, const int* __restrict__ devL,
    float* __restrict__ padphat)
{
  int b = blockIdx.x, tid = threadIdx.x;
  int sp = sp_arr[b], lp = sp_arr[b+1] - sp;
  float ax = 0.f, ay = 0.f;
  for (int m = 0; m < lp; m++){
    ushort2 vv = ((const ushort2*)(V + (size_t)(sp + m) * DD))[tid];
    ax += b2f(vv.x); ay += b2f(vv.y);
  }
  float invLp = 1.f / (float)devL[0];
  ((float2*)(padphat + (size_t)b * DD))[tid] = make_float2(ax * invLp, ay * invLp);
}

__global__ void prod_kernel(const bf16* __restrict__ a, const bf16* __restrict__ b,
                            bf16* __restrict__ c, size_t n8)
{
  size_t i = (size_t)blockIdx.x * blockDim.x + threadIdx.x;
  if (i >= n8) return;
  float fa[8], fb[8], fc[8];
  unpack8(((const uint4*)a)[i], fa);
  unpack8(((const uint4*)b)[i], fb);
  #pragma unroll
  for (int j = 0; j < 8; j++) fc[j] = fa[j] * fb[j];
  ((uint4*)c)[i] = pack8(fc);
}

__global__ void wcomb_kernel(const float* __restrict__ w1, float* __restrict__ Wp, float* __restrict__ Wh)
{
  int i = blockIdx.x * blockDim.x + threadIdx.x;
  if (i >= DD*DD) return;
  float a = w1[i], b = w1[i + DD*DD], c = w1[i + 2*DD*DD];
  Wp[i] = a + c;
  Wh[i] = b - c;
}

__global__ __launch_bounds__(256) void pool_kernel(
    const bf16* __restrict__ cmp, const float* __restrict__ padcmp,
    const int* __restrict__ sh_arr, const int* __restrict__ devL,
    float* __restrict__ smax, float* __restrict__ smean)
{
  int b = blockIdx.x, tid = threadIdx.x;
  int sh = sh_arr[b], lh = sh_arr[b+1] - sh;
  int Lh = devL[1];
  float mxx = -3.4e38f, mxy = -3.4e38f, smx = 0.f, smy = 0.f;
  for (int r = 0; r < lh; r++){
    ushort2 v = ((const ushort2*)(cmp + (size_t)(sh + r) * DD))[tid];
    float vx = b2f(v.x), vy = b2f(v.y);
    mxx = fmaxf(mxx, vx); mxy = fmaxf(mxy, vy);
    smx += vx; smy += vy;
  }
  int npad = Lh - lh;
  if (npad > 0){
    float2 p = ((const float2*)(padcmp + (size_t)b * DD))[tid];
    mxx = fmaxf(mxx, p.x); mxy = fmaxf(mxy, p.y);
    smx += npad * p.x; smy += npad * p.y;
  }
  float invLh = 1.f / (float)Lh;
  ((float2*)(smax + (size_t)b * DD))[tid] = make_float2(mxx, mxy);
  ((float2*)(smean + (size_t)b * DD))[tid] = make_float2(smx * invLh, smy * invLh);
}

__global__ __launch_bounds__(64) void logits_kernel(
    const float* __restrict__ z1, const float* __restrict__ c2, const float* __restrict__ cb2,
    float* __restrict__ out, int B)
{
  int b = blockIdx.x; int lane = threadIdx.x;
  const float4* zr = (const float4*)(z1 + (size_t)b * DD);
  float4 z0 = zr[lane*2], z1v = zr[lane*2+1];
  float zz[8] = {z0.x, z0.y, z0.z, z0.w, z1v.x, z1v.y, z1v.z, z1v.w};
  float p0 = 0.f, p1 = 0.f, p2 = 0.f;
  #pragma unroll
  for (int j = 0; j < 8; j++){
    int k = lane*8 + j;
    p0 += zz[j] * c2[k*3 + 0];
    p1 += zz[j] * c2[k*3 + 1];
    p2 += zz[j] * c2[k*3 + 2];
  }
  for (int off = 32; off; off >>= 1){
    p0 += __shfl_xor(p0, off); p1 += __shfl_xor(p1, off); p2 += __shfl_xor(p2, off);
  }
  if (lane == 0){
    out[1 + b*3 + 0] = p0 + cb2[0];
    out[1 + b*3 + 1] = p1 + cb2[1];
    out[1 + b*3 + 2] = p2 + cb2[2];
  }
}

__global__ __launch_bounds__(256) void loss_kernel(
    const float* __restrict__ dout, const float* __restrict__ label, float* __restrict__ out0, int n)
{
  __shared__ float red[256];
  int tid = threadIdx.x;
  float s = 0.f;
  for (int i = tid; i < n; i += 256){
    float z = dout[1 + i], y = label[i];
    s += fmaxf(z, 0.f) - z*y + log1pf(expf(-fabsf(z)));
  }
  red[tid] = s; __syncthreads();
  for (int st = 128; st; st >>= 1){ if (tid < st) red[tid] += red[tid+st]; __syncthreads(); }
  if (tid == 0) out0[0] = red[0] / (float)n;
}

// ------------------------------------------------------------------
extern "C" void kernel_launch(void* const* d_in, const int* in_sizes, int n_in,
                              void* d_out, int out_size, void* d_ws, size_t ws_size,
                              hipStream_t stream)
{
  const float* emb   = (const float*)d_in[0];
  const float* Wgat  = (const float*)d_in[1];
  const float* att_s = (const float*)d_in[2];
  const float* att_d = (const float*)d_in[3];
  const float* gbias = (const float*)d_in[4];
  const float* Wq    = (const float*)d_in[5];
  const float* Wk    = (const float*)d_in[6];
  const float* Wv    = (const float*)d_in[7];
  const float* w1    = (const float*)d_in[8];
  const float* b1    = (const float*)d_in[9];
  const float* w2    = (const float*)d_in[10];
  const float* b2    = (const float*)d_in[11];
  const float* c1    = (const float*)d_in[12];
  const float* cb1   = (const float*)d_in[13];
  const float* c2    = (const float*)d_in[14];
  const float* cb2   = (const float*)d_in[15];
  const float* label = (const float*)d_in[16];
  const int* xp = (const int*)d_in[17];
  const int* xh = (const int*)d_in[18];
  const int* ep = (const int*)d_in[19];
  const int* eh = (const int*)d_in[20];
  const int* bp = (const int*)d_in[21];
  const int* bh = (const int*)d_in[22];

  const int NP  = in_sizes[17], NH = in_sizes[18];
  const int N   = NP + NH;
  const int E2P = in_sizes[19] / 2, E2H = in_sizes[20] / 2;
  const int EALL = E2P + E2H + N;
  const int B = in_sizes[16] / 3;

  char* wptr = (char*)d_ws;
  auto alloc = [&](size_t bytes) -> void* {
    void* p = (void*)wptr; wptr += (bytes + 255) & ~(size_t)255; return p;
  };
  bf16* bufX = (bf16*)alloc((size_t)N  * DD * 2);  // node features / enc; p-half later = S,P
  bf16* bufY = (bf16*)alloc((size_t)N  * DD * 2);  // xw ; K ; Vt ; hidden
  bf16* bufV = (bf16*)alloc((size_t)NP * DD * 2);  // V ; later cmp
  bf16* bufQ = (bf16*)alloc((size_t)NH * DD * 2);  // Q ; later p_hat*h
  bf16* bufP = (bf16*)alloc((size_t)NH * DD * 2);  // p_hat
  float* a_s  = (float*)alloc((size_t)N * 8 * 4);
  float* a_d  = (float*)alloc((size_t)N * 8 * 4);
  int* counts   = (int*)alloc((size_t)N * 4);
  int* csr_off  = (int*)alloc((size_t)(N + 1) * 4);
  int* cursor   = (int*)alloc((size_t)N * 4);
  int* csr_src  = (int*)alloc((size_t)EALL * 4);
  int* starts_p = (int*)alloc((size_t)(B + 1) * 4);
  int* starts_h = (int*)alloc((size_t)(B + 1) * 4);
  int* devL     = (int*)alloc(64);
  float* padphat = (float*)alloc((size_t)B * DD * 4);
  float* padhid  = (float*)alloc((size_t)B * DD * 4);
  float* padcmp  = (float*)alloc((size_t)B * DD * 4);
  float* smax  = (float*)alloc((size_t)B * DD * 4);
  float* smean = (float*)alloc((size_t)B * DD * 4);
  float* z1    = (float*)alloc((size_t)B * DD * 4);
  float* Wpc   = (float*)alloc((size_t)DD * DD * 4);
  float* Whc   = (float*)alloc((size_t)DD * DD * 4);
  bf16* WT_gat = (bf16*)alloc((size_t)DD * DD * 2);
  bf16* WT_q   = (bf16*)alloc((size_t)DD * DD * 2);
  bf16* WT_k   = (bf16*)alloc((size_t)DD * DD * 2);
  bf16* WT_v   = (bf16*)alloc((size_t)DD * DD * 2);
  bf16* WT_pc  = (bf16*)alloc((size_t)DD * DD * 2);
  bf16* WT_hc  = (bf16*)alloc((size_t)DD * DD * 2);
  bf16* WT_1d  = (bf16*)alloc((size_t)DD * DD * 2);
  bf16* WT_2   = (bf16*)alloc((size_t)DD * DD * 2);

  hipMemsetAsync(counts, 0, (size_t)N * 4, stream);
  hipMemsetAsync(cursor, 0, (size_t)N * 4, stream);

  embed_kernel<<<N, 128, 0, stream>>>(emb, xp, xh, bufX, NP, N);
  mark_starts<<<(NP + 255)/256, 256, 0, stream>>>(bp, starts_p, NP, B);
  mark_starts<<<(NH + 255)/256, 256, 0, stream>>>(bh, starts_h, NH, B);
  compute_maxlen<<<1, 256, 0, stream>>>(starts_p, starts_h, B, devL);
  edge_count<<<(EALL + 255)/256, 256, 0, stream>>>(ep, eh, E2P, E2H, NP, N, counts);
  exscan<<<1, 1024, 0, stream>>>(counts, csr_off, N);
  edge_fill<<<(EALL + 255)/256, 256, 0, stream>>>(ep, eh, E2P, E2H, NP, N, csr_off, cursor, csr_src);
  wcomb_kernel<<<(DD*DD + 255)/256, 256, 0, stream>>>(w1, Wpc, Whc);

  dim3 tg(8, 8);
  transpose_w<<<tg, 256, 0, stream>>>(Wgat, WT_gat);
  transpose_w<<<tg, 256, 0, stream>>>(Wq,   WT_q);
  transpose_w<<<tg, 256, 0, stream>>>(Wk,   WT_k);
  transpose_w<<<tg, 256, 0, stream>>>(Wv,   WT_v);
  transpose_w<<<tg, 256, 0, stream>>>(Wpc,  WT_pc);
  transpose_w<<<tg, 256, 0, stream>>>(Whc,  WT_hc);
  transpose_w<<<tg, 256, 0, stream>>>(w1 + (size_t)3*DD*DD, WT_1d);
  transpose_w<<<tg, 256, 0, stream>>>(w2,   WT_2);

  auto gemmM = [&](const bf16* A, const bf16* WT, const float* bias, bf16* Cv, int M, int flags){
    dim3 g((unsigned)((M + 127)/128), 4);
    gemm_mfma<<<g, 256, 0, stream>>>(A, WT, bias, Cv, M, flags);
  };
  auto gemmF = [&](const float* A, const float* Wm, const float* bias, float* Cv, int M, int flags){
    dim3 g((unsigned)((M + 63)/64), DD/64);
    gemm64<<<g, 256, 0, stream>>>(A, Wm, bias, Cv, M, DD, flags);
  };

  // 3 shared-weight GAT layers on the combined graph
  for (int l = 0; l < 3; l++){
    gemmM(bufX, WT_gat, nullptr, bufY, N, 0);
    gat_attn_coeff<<<N, 64, 0, stream>>>(bufY, att_s, att_d, a_s, a_d, N);
    gat_aggregate<<<N, 64, 0, stream>>>(bufY, a_s, a_d, csr_off, csr_src, gbias, bufX, N);
  }

  const bf16* h_enc = bufX + (size_t)NP * DD;
  gemmM(h_enc, WT_q, nullptr, bufQ, NH, 0);
  gemmM(bufX,  WT_k, nullptr, bufY, NP, 0);   // K
  gemmM(bufX,  WT_v, nullptr, bufV, NP, 0);   // V

  // --- MFMA cross-attention ---
  // S,P overlay the (now dead) p_enc half of bufX; Vt overlays bufY once K consumed.
  float* Sbuf = (float*)bufX;                               // [NH][384] f32
  bf16*  Pbuf = (bf16*)((char*)bufX + (((size_t)NH*384*4 + 255) & ~(size_t)255)); // [NH][416] bf16
  const int NPpad = (NP + 384 + 63) & ~63;
  bf16* Vt = bufY;

  score_mfma<<<dim3(B, 2, 6), 256, 0, stream>>>(bufQ, bufY, starts_p, starts_h, Sbuf, NH, NP);
  transpose_v<<<dim3((NP + 63)/64, 8), 256, 0, stream>>>(bufV, Vt, NP, NPpad);
  softmax_rows<<<(NH + 3)/4, 256, 0, stream>>>(Sbuf, Pbuf, starts_p, bh, NH);
  pv_mfma<<<dim3(B, 2, 4), 256, 0, stream>>>(Pbuf, Vt, starts_p, starts_h, bufP, NH, NPpad);
  vsum_kernel<<<B, 256, 0, stream>>>(bufV, starts_p, devL, padphat);

  size_t n8 = (size_t)NH * (DD/8);
  prod_kernel<<<(unsigned)((n8 + 255)/256), 256, 0, stream>>>(bufP, h_enc, bufQ, n8);

  bf16* hid = bufY;                        // Vt is dead after pv_mfma
  gemmM(bufP, WT_pc, b1, hid, NH, 0);
  gemmM(h_enc, WT_hc, nullptr, hid, NH, 1);
  gemmM(bufQ, WT_1d, nullptr, hid, NH, 1 | 2);  // + relu
  bf16* cmp = bufV;                        // V is dead
  gemmM(hid, WT_2, b2, cmp, NH, 0);

  gemmF(padphat, Wpc, b1, padhid, B, 2);   // pad rows: feat = [p,0,p,0]
  gemmF(padhid, w2, b2, padcmp, B, 0);

  pool_kernel<<<B, 256, 0, stream>>>(cmp, padcmp, starts_h, devL, smax, smean);

  gemmF(smax,  c1,                 cb1,     z1, B, 0);
  gemmF(smean, c1 + (size_t)DD*DD, nullptr, z1, B, 1 | 2);
  logits_kernel<<<B, 64, 0, stream>>>(z1, c2, cb2, (float*)d_out, B);
  loss_kernel<<<1, 256, 0, stream>>>((float*)d_out, label, (float*)d_out, B * 3);
}

// Round 9
// 1806.175 us; speedup vs baseline: 2.7495x; 1.0750x over previous
//
#include <hip/hip_runtime.h>
#include <cstdint>
#include <cstddef>

#define DD 512
#define SLOPE 0.2f

typedef unsigned short bf16;
typedef __attribute__((ext_vector_type(8))) short short8v;  // 8 bf16 (4 VGPRs)
typedef __attribute__((ext_vector_type(4))) float f32x4;

__device__ __forceinline__ float b2f(unsigned short u){
  union { float f; unsigned int i; } v; v.i = ((unsigned int)u) << 16; return v.f;
}
__device__ __forceinline__ unsigned short f2b(float f){
  union { float f; unsigned int i; } v; v.f = f;
  unsigned int r = v.i + 0x7FFFu + ((v.i >> 16) & 1u);
  return (unsigned short)(r >> 16);
}
__device__ __forceinline__ void unpack8(uint4 u, float* f){
  f[0]=b2f((unsigned short)(u.x & 0xFFFFu)); f[1]=b2f((unsigned short)(u.x >> 16));
  f[2]=b2f((unsigned short)(u.y & 0xFFFFu)); f[3]=b2f((unsigned short)(u.y >> 16));
  f[4]=b2f((unsigned short)(u.z & 0xFFFFu)); f[5]=b2f((unsigned short)(u.z >> 16));
  f[6]=b2f((unsigned short)(u.w & 0xFFFFu)); f[7]=b2f((unsigned short)(u.w >> 16));
}
__device__ __forceinline__ uint4 pack8(const float* f){
  uint4 u;
  u.x = (unsigned int)f2b(f[0]) | ((unsigned int)f2b(f[1]) << 16);
  u.y = (unsigned int)f2b(f[2]) | ((unsigned int)f2b(f[3]) << 16);
  u.z = (unsigned int)f2b(f[4]) | ((unsigned int)f2b(f[5]) << 16);
  u.w = (unsigned int)f2b(f[6]) | ((unsigned int)f2b(f[7]) << 16);
  return u;
}

// ------------------------------------------------------------------
__global__ __launch_bounds__(128) void embed_kernel(
    const float* __restrict__ emb, const int* __restrict__ xp, const int* __restrict__ xh,
    bf16* __restrict__ x, int NP, int N)
{
  int row = blockIdx.x; if (row >= N) return;
  int idx = (row < NP) ? xp[row] : xh[row - NP];
  float4 v = ((const float4*)(emb + (size_t)idx * DD))[threadIdx.x];
  ushort4 o; o.x = f2b(v.x); o.y = f2b(v.y); o.z = f2b(v.z); o.w = f2b(v.w);
  ((ushort4*)(x + (size_t)row * DD))[threadIdx.x] = o;
}

// ------------------------------------------------------------------
__global__ void mark_starts(const int* __restrict__ batch, int* __restrict__ starts, int n, int B)
{
  int i = blockIdx.x * blockDim.x + threadIdx.x; if (i >= n) return;
  int b = batch[i];
  if (i == 0) starts[0] = 0;
  else if (batch[i-1] != b) starts[b] = i;
  if (i == n-1) starts[B] = n;
}

__global__ __launch_bounds__(256) void compute_maxlen(
    const int* __restrict__ sp, const int* __restrict__ sh, int B, int* __restrict__ devL)
{
  __shared__ int red[256];
  int tid = threadIdx.x;
  int ml = 0;
  for (int b = tid; b < B; b += 256) ml = max(ml, sp[b+1]-sp[b]);
  red[tid] = ml; __syncthreads();
  for (int s = 128; s; s >>= 1){ if (tid < s) red[tid] = max(red[tid], red[tid+s]); __syncthreads(); }
  if (tid == 0) devL[0] = red[0];
  __syncthreads();
  ml = 0;
  for (int b = tid; b < B; b += 256) ml = max(ml, sh[b+1]-sh[b]);
  red[tid] = ml; __syncthreads();
  for (int s = 128; s; s >>= 1){ if (tid < s) red[tid] = max(red[tid], red[tid+s]); __syncthreads(); }
  if (tid == 0) devL[1] = red[0];
}

// ------------------------------------------------------------------
__global__ void edge_count(const int* __restrict__ ep, const int* __restrict__ eh,
                           int E2P, int E2H, int NP, int N, int* __restrict__ counts)
{
  int e = blockIdx.x * blockDim.x + threadIdx.x;
  int EALL = E2P + E2H + N;
  if (e >= EALL) return;
  int dst;
  if (e < E2P)            dst = ep[E2P + e];
  else if (e < E2P + E2H) dst = NP + eh[E2H + (e - E2P)];
  else                    dst = e - E2P - E2H;
  atomicAdd(&counts[dst], 1);
}

__global__ void edge_fill(const int* __restrict__ ep, const int* __restrict__ eh,
                          int E2P, int E2H, int NP, int N,
                          const int* __restrict__ off, int* __restrict__ cursor,
                          int* __restrict__ csr_src)
{
  int e = blockIdx.x * blockDim.x + threadIdx.x;
  int EALL = E2P + E2H + N;
  if (e >= EALL) return;
  int src, dst;
  if (e < E2P)            { src = ep[e];                 dst = ep[E2P + e]; }
  else if (e < E2P + E2H) { int j = e - E2P; src = NP + eh[j]; dst = NP + eh[E2H + j]; }
  else                    { src = dst = e - E2P - E2H; }
  int pos = atomicAdd(&cursor[dst], 1);
  csr_src[off[dst] + pos] = src;
}

// ------------------------------------------------------------------
// hierarchical exclusive scan: 2048 elems/block
__global__ __launch_bounds__(256) void scan_partial(
    const int* __restrict__ in, int* __restrict__ out, int* __restrict__ bsums, int n)
{
  __shared__ int wsum[4];
  int blk = blockIdx.x, tid = threadIdx.x;
  int base = blk * 2048 + tid * 8;
  int v[8]; int s = 0;
  #pragma unroll
  for (int j = 0; j < 8; j++){
    v[j] = (base + j < n) ? in[base + j] : 0;
    s += v[j];
  }
  int lane = tid & 63, wid = tid >> 6;
  int x = s;
  for (int off = 1; off < 64; off <<= 1){
    int y = __shfl_up(x, off);
    if (lane >= off) x += y;
  }
  if (lane == 63) wsum[wid] = x;
  __syncthreads();
  if (tid == 0){
    int acc = 0;
    #pragma unroll
    for (int w = 0; w < 4; w++){ int t = wsum[w]; wsum[w] = acc; acc += t; }
    bsums[blk] = acc;
  }
  __syncthreads();
  int run = x - s + wsum[wid];   // exclusive prefix of this thread within block
  #pragma unroll
  for (int j = 0; j < 8; j++){
    if (base + j < n) out[base + j] = run;
    run += v[j];
  }
}

// scan block sums (nb <= 1024) exclusive in-place; write grand total to *total
__global__ __launch_bounds__(1024) void scan_sums(int* __restrict__ bsums, int nb, int* __restrict__ total)
{
  __shared__ int buf[1024];
  int tid = threadIdx.x;
  int x = (tid < nb) ? bsums[tid] : 0;
  buf[tid] = x;
  __syncthreads();
  for (int off = 1; off < 1024; off <<= 1){
    int v = (tid >= off) ? buf[tid - off] : 0;
    __syncthreads();
    buf[tid] += v;
    __syncthreads();
  }
  if (tid < nb) bsums[tid] = buf[tid] - x;
  if (tid == 0) total[0] = buf[nb - 1];
}

__global__ __launch_bounds__(256) void scan_add(int* __restrict__ out, const int* __restrict__ bsums, int n)
{
  int blk = blockIdx.x;
  int base = blk * 2048 + threadIdx.x * 8;
  int add = bsums[blk];
  #pragma unroll
  for (int j = 0; j < 8; j++){
    if (base + j < n) out[base + j] += add;
  }
}

// ------------------------------------------------------------------
// 64x64-tile transpose + f32->bf16: dst[n][k] = bf16(src[k][n]); both 512x512
__global__ __launch_bounds__(256) void transpose_w(const float* __restrict__ src, bf16* __restrict__ dst)
{
  __shared__ float t[64][65];
  int k0 = blockIdx.x * 64, n0 = blockIdx.y * 64;
  int tid = threadIdx.x;
  int r = tid >> 4, c4 = (tid & 15) * 4;
  #pragma unroll
  for (int p = 0; p < 4; p++){
    int row = r + p*16;
    float4 v = *(const float4*)(src + (size_t)(k0 + row) * DD + n0 + c4);
    t[c4+0][row] = v.x; t[c4+1][row] = v.y; t[c4+2][row] = v.z; t[c4+3][row] = v.w;
  }
  __syncthreads();
  #pragma unroll
  for (int p = 0; p < 4; p++){
    int row = r + p*16;  // n-within-tile
    ushort4 o;
    o.x = f2b(t[row][c4+0]); o.y = f2b(t[row][c4+1]);
    o.z = f2b(t[row][c4+2]); o.w = f2b(t[row][c4+3]);
    *(ushort4*)(dst + (size_t)(n0 + row) * DD + k0 + c4) = o;
  }
}

// bf16 [NP][512] -> bf16 [512][NPpad] transpose (Vt for PV MFMA)
__global__ __launch_bounds__(256) void transpose_v(
    const bf16* __restrict__ V, bf16* __restrict__ Vt, int NP, int NPpad)
{
  __shared__ bf16 t[64][72];
  int r0 = blockIdx.x * 64, c0 = blockIdx.y * 64;
  int tid = threadIdx.x;
  int row = tid >> 2, cc = (tid & 3) * 16;
  uint4 v0 = {0,0,0,0}, v1 = {0,0,0,0};
  if (r0 + row < NP){
    v0 = *(const uint4*)(V + (size_t)(r0+row) * DD + c0 + cc);
    v1 = *(const uint4*)(V + (size_t)(r0+row) * DD + c0 + cc + 8);
  }
  *(uint4*)&t[row][cc]   = v0;
  *(uint4*)&t[row][cc+8] = v1;
  __syncthreads();
  int col = tid >> 2, rr = (tid & 3) * 16;
  ushort o[16];
  #pragma unroll
  for (int j = 0; j < 16; j++) o[j] = t[rr + j][col];
  *(uint4*)(Vt + (size_t)(c0+col) * NPpad + r0 + rr)     = *(uint4*)&o[0];
  *(uint4*)(Vt + (size_t)(c0+col) * NPpad + r0 + rr + 8) = *(uint4*)&o[8];
}

// ------------------------------------------------------------------
// MFMA bf16 GEMM: C[M,512] = A[M,512] @ W[512,512] (+bias)(+=C)(relu)
__global__ __launch_bounds__(256) void gemm_mfma(
    const bf16* __restrict__ A, const bf16* __restrict__ WT, const float* __restrict__ bias,
    bf16* __restrict__ C, int M, int flags)
{
  __shared__ __align__(16) bf16 Asub[128*64];
  __shared__ __align__(16) bf16 Bsub[128*64];
  int tid = threadIdx.x;
  int wave = tid >> 6, lane = tid & 63;
  int wr = wave >> 1, wc = wave & 1;
  int row0 = blockIdx.x * 128, col0 = blockIdx.y * 128;
  int l15 = lane & 15, l4 = lane >> 4;
  f32x4 acc[4][4];
  #pragma unroll
  for (int m = 0; m < 4; m++)
    #pragma unroll
    for (int n = 0; n < 4; n++)
      acc[m][n] = (f32x4){0.f, 0.f, 0.f, 0.f};

  for (int k0 = 0; k0 < DD; k0 += 64){
    #pragma unroll
    for (int p = 0; p < 2; p++){
      int chunk = tid + p*256;
      int r = chunk >> 2, cb = chunk & 3;
      uint4 av = *(const uint4*)(A  + (size_t)(row0 + r) * DD + k0 + cb*8);
      uint4 bv = *(const uint4*)(WT + (size_t)(col0 + r) * DD + k0 + cb*8);
      int off = r*128 + ((cb*16) ^ ((r&7)<<4));
      *(uint4*)((char*)Asub + off) = av;
      *(uint4*)((char*)Bsub + off) = bv;
    }
    __syncthreads();
    #pragma unroll
    for (int kk = 0; kk < 2; kk++){
      int colb = kk*64 + (l4<<4);
      short8v af[4], bfr[4];
      #pragma unroll
      for (int m = 0; m < 4; m++){
        int ar = wr*64 + m*16 + l15;
        af[m]  = *(const short8v*)((const char*)Asub + ar*128 + (colb ^ ((ar&7)<<4)));
        int br = wc*64 + m*16 + l15;
        bfr[m] = *(const short8v*)((const char*)Bsub + br*128 + (colb ^ ((br&7)<<4)));
      }
      #pragma unroll
      for (int m = 0; m < 4; m++)
        #pragma unroll
        for (int n = 0; n < 4; n++)
          acc[m][n] = __builtin_amdgcn_mfma_f32_16x16x32_bf16(af[m], bfr[n], acc[m][n], 0, 0, 0);
    }
    __syncthreads();
  }

  #pragma unroll
  for (int m = 0; m < 4; m++){
    #pragma unroll
    for (int n = 0; n < 4; n++){
      int gc = col0 + wc*64 + n*16 + l15;
      float bv = bias ? bias[gc] : 0.f;
      #pragma unroll
      for (int r = 0; r < 4; r++){
        int gr = row0 + wr*64 + m*16 + l4*4 + r;
        if (gr < M){
          float v = acc[m][n][r] + bv;
          bf16* cp = C + (size_t)gr * DD + gc;
          if (flags & 1) v += b2f(*cp);
          if (flags & 2) v = fmaxf(v, 0.f);
          *cp = f2b(v);
        }
      }
    }
  }
}

// ------------------------------------------------------------------
// scores S[sh+r][c] = Q[sh+r,:] . K[sp+c,:]  (per-graph 64x64 tiles)
__global__ __launch_bounds__(256) void score_mfma(
    const bf16* __restrict__ Q, const bf16* __restrict__ K,
    const int* __restrict__ sp_arr, const int* __restrict__ sh_arr,
    float* __restrict__ S, int NH, int NP)
{
  int b = blockIdx.x;
  int sh = sh_arr[b], lh = sh_arr[b+1] - sh;
  int sp = sp_arr[b], lp = sp_arr[b+1] - sp;
  int qt = blockIdx.y * 64, kt = blockIdx.z * 64;
  if (qt >= lh || kt >= lp) return;
  int tid = threadIdx.x, wave = tid >> 6, lane = tid & 63;
  int wr = (wave >> 1) * 32, wc = (wave & 1) * 32;
  int l15 = lane & 15, l4 = lane >> 4;
  f32x4 acc[2][2];
  #pragma unroll
  for (int m = 0; m < 2; m++)
    #pragma unroll
    for (int n = 0; n < 2; n++)
      acc[m][n] = (f32x4){0.f,0.f,0.f,0.f};
  int ar[2], br[2];
  #pragma unroll
  for (int m = 0; m < 2; m++) ar[m] = min(sh + qt + wr + m*16 + l15, NH-1);
  #pragma unroll
  for (int n = 0; n < 2; n++) br[n] = min(sp + kt + wc + n*16 + l15, NP-1);
  for (int k0 = 0; k0 < DD; k0 += 32){
    short8v af[2], bv[2];
    #pragma unroll
    for (int m = 0; m < 2; m++) af[m] = *(const short8v*)(Q + (size_t)ar[m]*DD + k0 + l4*8);
    #pragma unroll
    for (int n = 0; n < 2; n++) bv[n] = *(const short8v*)(K + (size_t)br[n]*DD + k0 + l4*8);
    #pragma unroll
    for (int m = 0; m < 2; m++)
      #pragma unroll
      for (int n = 0; n < 2; n++)
        acc[m][n] = __builtin_amdgcn_mfma_f32_16x16x32_bf16(af[m], bv[n], acc[m][n], 0, 0, 0);
  }
  #pragma unroll
  for (int m = 0; m < 2; m++)
    #pragma unroll
    for (int n = 0; n < 2; n++)
      #pragma unroll
      for (int i = 0; i < 4; i++){
        int rr = qt + wr + m*16 + l4*4 + i;
        int cc = kt + wc + n*16 + l15;
        if (rr < lh && cc < lp) S[(size_t)(sh+rr)*384 + cc] = acc[m][n][i];
      }
}

// masked softmax over S rows -> P bf16, shifted by d = sp&7 (stride 416)
__global__ __launch_bounds__(256) void softmax_rows(
    const float* __restrict__ S, bf16* __restrict__ P,
    const int* __restrict__ sp_arr, const int* __restrict__ hbatch, int NH)
{
  __shared__ float sm[4][384];
  int w = threadIdx.x >> 6, lane = threadIdx.x & 63;
  int i = blockIdx.x * 4 + w; if (i >= NH) return;
  int b = hbatch[i];
  int sp = sp_arr[b], lp = sp_arr[b+1] - sp;
  int d = sp & 7;
  const float scale = 0.044194173824159216f; // 1/sqrt(512)
  float e[6]; float mx = -3.4e38f;
  #pragma unroll
  for (int j = 0; j < 6; j++){
    int c = j*64 + lane;
    float v = (c < lp) ? S[(size_t)i*384 + c] * scale : -1e30f;
    e[j] = v; mx = fmaxf(mx, v);
  }
  for (int off = 32; off; off >>= 1) mx = fmaxf(mx, __shfl_xor(mx, off));
  float sum = 0.f;
  #pragma unroll
  for (int j = 0; j < 6; j++){ float x = __expf(e[j] - mx); e[j] = x; sum += x; }
  for (int off = 32; off; off >>= 1) sum += __shfl_xor(sum, off);
  float inv = 1.f / sum;
  #pragma unroll
  for (int j = 0; j < 6; j++) sm[w][j*64 + lane] = e[j];
  #pragma unroll
  for (int j = 0; j < 7; j++){
    int o = j*64 + lane;
    if (o < 416){
      int c = o - d;
      float val = (c >= 0 && c < lp) ? sm[w][c] * inv : 0.f;
      P[(size_t)i*416 + o] = f2b(val);
    }
  }
}

// p_hat[sh+r][col] = sum_k P[sh+r][k] * Vt[col][jp0+k]
__global__ __launch_bounds__(256) void pv_mfma(
    const bf16* __restrict__ P, const bf16* __restrict__ Vt,
    const int* __restrict__ sp_arr, const int* __restrict__ sh_arr,
    bf16* __restrict__ out, int NH, int NPpad)
{
  int b = blockIdx.x;
  int sh = sh_arr[b], lh = sh_arr[b+1] - sh;
  int sp = sp_arr[b], lp = sp_arr[b+1] - sp;
  int qt = blockIdx.y * 64;
  if (qt >= lh) return;
  int ct = blockIdx.z * 128;
  int d = sp & 7, jp0 = sp - d;
  int tid = threadIdx.x, wave = tid >> 6, lane = tid & 63;
  int wr = (wave >> 1) * 32, wc = (wave & 1) * 64;
  int l15 = lane & 15, l4 = lane >> 4;
  f32x4 acc[2][4];
  #pragma unroll
  for (int m = 0; m < 2; m++)
    #pragma unroll
    for (int n = 0; n < 4; n++)
      acc[m][n] = (f32x4){0.f,0.f,0.f,0.f};
  int ar[2];
  #pragma unroll
  for (int m = 0; m < 2; m++) ar[m] = min(sh + qt + wr + m*16 + l15, NH-1);
  int kmax = (lp + d + 31) & ~31;
  for (int k0 = 0; k0 < kmax; k0 += 32){
    short8v af[2], bv[4];
    #pragma unroll
    for (int m = 0; m < 2; m++) af[m] = *(const short8v*)(P + (size_t)ar[m]*416 + k0 + l4*8);
    #pragma unroll
    for (int n = 0; n < 4; n++){
      int vc = ct + wc + n*16 + l15;
      bv[n] = *(const short8v*)(Vt + (size_t)vc*NPpad + jp0 + k0 + l4*8);
    }
    #pragma unroll
    for (int m = 0; m < 2; m++)
      #pragma unroll
      for (int n = 0; n < 4; n++)
        acc[m][n] = __builtin_amdgcn_mfma_f32_16x16x32_bf16(af[m], bv[n], acc[m][n], 0, 0, 0);
  }
  #pragma unroll
  for (int m = 0; m < 2; m++)
    #pragma unroll
    for (int n = 0; n < 4; n++)
      #pragma unroll
      for (int i = 0; i < 4; i++){
        int rr = qt + wr + m*16 + l4*4 + i;
        int cc = ct + wc + n*16 + l15;
        if (rr < lh) out[(size_t)(sh+rr)*DD + cc] = f2b(acc[m][n][i]);
      }
}

// ------------------------------------------------------------------
// f32 tiled GEMM (small-M paths only: pad rows, classifier)
__global__ __launch_bounds__(256) void gemm64(
    const float* __restrict__ A, const float* __restrict__ W, const float* __restrict__ bias,
    float* __restrict__ C, int M, int Ncol, int flags)
{
  __shared__ float As[16][65];
  __shared__ float Bs[16][64];
  int tid = threadIdx.x;
  int tx = tid & 15, ty = tid >> 4;
  int row0 = blockIdx.x * 64, col0 = blockIdx.y * 64;
  float acc[4][4] = {};
  int lr = tid >> 2, lk = (tid & 3) * 4;
  int bk = tid >> 4, bn = (tid & 15) * 4;
  for (int k0 = 0; k0 < DD; k0 += 16){
    float a0 = 0.f, a1 = 0.f, a2 = 0.f, a3 = 0.f;
    int gr = row0 + lr;
    if (gr < M){
      float4 av = *(const float4*)(A + (size_t)gr * DD + k0 + lk);
      a0 = av.x; a1 = av.y; a2 = av.z; a3 = av.w;
    }
    As[lk+0][lr] = a0; As[lk+1][lr] = a1; As[lk+2][lr] = a2; As[lk+3][lr] = a3;
    *(float4*)&Bs[bk][bn] = *(const float4*)(W + (size_t)(k0 + bk) * Ncol + col0 + bn);
    __syncthreads();
    #pragma unroll
    for (int k = 0; k < 16; k++){
      float x0 = As[k][ty*4+0], x1 = As[k][ty*4+1], x2 = As[k][ty*4+2], x3 = As[k][ty*4+3];
      float y0 = Bs[k][tx*4+0], y1 = Bs[k][tx*4+1], y2 = Bs[k][tx*4+2], y3 = Bs[k][tx*4+3];
      acc[0][0] += x0*y0; acc[0][1] += x0*y1; acc[0][2] += x0*y2; acc[0][3] += x0*y3;
      acc[1][0] += x1*y0; acc[1][1] += x1*y1; acc[1][2] += x1*y2; acc[1][3] += x1*y3;
      acc[2][0] += x2*y0; acc[2][1] += x2*y1; acc[2][2] += x2*y2; acc[2][3] += x2*y3;
      acc[3][0] += x3*y0; acc[3][1] += x3*y1; acc[3][2] += x3*y2; acc[3][3] += x3*y3;
    }
    __syncthreads();
  }
  #pragma unroll
  for (int i = 0; i < 4; i++){
    int gr = row0 + ty*4 + i; if (gr >= M) continue;
    float r0 = acc[i][0], r1 = acc[i][1], r2 = acc[i][2], r3 = acc[i][3];
    if (bias){
      float4 bv = *(const float4*)(bias + col0 + tx*4);
      r0 += bv.x; r1 += bv.y; r2 += bv.z; r3 += bv.w;
    }
    float4* cp = (float4*)(C + (size_t)gr * Ncol + col0 + tx*4);
    if (flags & 1){
      float4 o = *cp;
      r0 += o.x; r1 += o.y; r2 += o.z; r3 += o.w;
    }
    if (flags & 2){
      r0 = fmaxf(r0, 0.f); r1 = fmaxf(r1, 0.f); r2 = fmaxf(r2, 0.f); r3 = fmaxf(r3, 0.f);
    }
    *cp = make_float4(r0, r1, r2, r3);
  }
}

// ------------------------------------------------------------------
__global__ __launch_bounds__(64) void gat_attn_coeff(
    const bf16* __restrict__ xw, const float* __restrict__ att_src, const float* __restrict__ att_dst,
    float* __restrict__ a_s, float* __restrict__ a_d, int N)
{
  int n = blockIdx.x; if (n >= N) return;
  int lane = threadIdx.x;
  float x[8];
  unpack8(*(const uint4*)(xw + (size_t)n * DD + lane * 8), x);
  const float4* sr = (const float4*)(att_src + lane * 8);
  const float4* dr = (const float4*)(att_dst + lane * 8);
  float4 s0 = sr[0], s1 = sr[1], d0 = dr[0], d1 = dr[1];
  float ps = x[0]*s0.x + x[1]*s0.y + x[2]*s0.z + x[3]*s0.w
           + x[4]*s1.x + x[5]*s1.y + x[6]*s1.z + x[7]*s1.w;
  float pd = x[0]*d0.x + x[1]*d0.y + x[2]*d0.z + x[3]*d0.w
           + x[4]*d1.x + x[5]*d1.y + x[6]*d1.z + x[7]*d1.w;
  for (int off = 1; off < 8; off <<= 1){ ps += __shfl_xor(ps, off); pd += __shfl_xor(pd, off); }
  if ((lane & 7) == 0){
    a_s[n*8 + (lane>>3)] = ps;
    a_d[n*8 + (lane>>3)] = pd;
  }
}

__global__ __launch_bounds__(64) void gat_aggregate(
    const bf16* __restrict__ xw, const float* __restrict__ a_s, const float* __restrict__ a_d,
    const int* __restrict__ csr_off, const int* __restrict__ csr_src,
    const float* __restrict__ bias, bf16* __restrict__ out, int N)
{
  int n = blockIdx.x; if (n >= N) return;
  int lane = threadIdx.x;
  int h = lane >> 3;
  int o0 = csr_off[n], deg = csr_off[n+1] - o0;
  float adh = a_d[n*8 + h];
  float mx = -3.4e38f;
  for (int e = 0; e < deg; e++){
    int s = csr_src[o0 + e];
    float v = a_s[s*8 + h] + adh;
    v = (v >= 0.f) ? v : SLOPE * v;
    mx = fmaxf(mx, v);
  }
  float den = 0.f;
  for (int e = 0; e < deg; e++){
    int s = csr_src[o0 + e];
    float v = a_s[s*8 + h] + adh;
    v = (v >= 0.f) ? v : SLOPE * v;
    den += __expf(v - mx);
  }
  float inv = 1.f / (den + 1e-16f);
  float A[8] = {};
  for (int e = 0; e < deg; e++){
    int s = csr_src[o0 + e];
    float v = a_s[s*8 + h] + adh;
    v = (v >= 0.f) ? v : SLOPE * v;
    float al = __expf(v - mx) * inv;
    float x[8];
    unpack8(*(const uint4*)(xw + (size_t)s * DD + lane * 8), x);
    #pragma unroll
    for (int j = 0; j < 8; j++) A[j] += al * x[j];
  }
  const float4* bq = (const float4*)(bias + lane * 8);
  float4 b0 = bq[0], b1 = bq[1];
  float r[8] = { A[0]+b0.x, A[1]+b0.y, A[2]+b0.z, A[3]+b0.w,
                 A[4]+b1.x, A[5]+b1.y, A[6]+b1.z, A[7]+b1.w };
  *(uint4*)(out + (size_t)n * DD + lane * 8) = pack8(r);
}

// ------------------------------------------------------------------
__global__ __launch_bounds__(256) void vsum_kernel(
    const bf16* __restrict__ V, const int* __restrict__ sp_arr, const int* __restrict__ devL,
    float* __restrict__ padphat)
{
  int b = blockIdx.x, tid = threadIdx.x;
  int sp = sp_arr[b], lp = sp_arr[b+1] - sp;
  float ax = 0.f, ay = 0.f;
  for (int m = 0; m < lp; m++){
    ushort2 vv = ((const ushort2*)(V + (size_t)(sp + m) * DD))[tid];
    ax += b2f(vv.x); ay += b2f(vv.y);
  }
  float invLp = 1.f / (float)devL[0];
  ((float2*)(padphat + (size_t)b * DD))[tid] = make_float2(ax * invLp, ay * invLp);
}

__global__ void prod_kernel(const bf16* __restrict__ a, const bf16* __restrict__ b,
                            bf16* __restrict__ c, size_t n8)
{
  size_t i = (size_t)blockIdx.x * blockDim.x + threadIdx.x;
  if (i >= n8) return;
  float fa[8], fb[8], fc[8];
  unpack8(((const uint4*)a)[i], fa);
  unpack8(((const uint4*)b)[i], fb);
  #pragma unroll
  for (int j = 0; j < 8; j++) fc[j] = fa[j] * fb[j];
  ((uint4*)c)[i] = pack8(fc);
}

__global__ void wcomb_kernel(const float* __restrict__ w1, float* __restrict__ Wp, float* __restrict__ Wh)
{
  int i = blockIdx.x * blockDim.x + threadIdx.x;
  if (i >= DD*DD) return;
  float a = w1[i], b = w1[i + DD*DD], c = w1[i + 2*DD*DD];
  Wp[i] = a + c;
  Wh[i] = b - c;
}

__global__ __launch_bounds__(256) void pool_kernel(
    const bf16* __restrict__ cmp, const float* __restrict__ padcmp,
    const int* __restrict__ sh_arr, const int* __restrict__ devL,
    float* __restrict__ smax, float* __restrict__ smean)
{
  int b = blockIdx.x, tid = threadIdx.x;
  int sh = sh_arr[b], lh = sh_arr[b+1] - sh;
  int Lh = devL[1];
  float mxx = -3.4e38f, mxy = -3.4e38f, smx = 0.f, smy = 0.f;
  for (int r = 0; r < lh; r++){
    ushort2 v = ((const ushort2*)(cmp + (size_t)(sh + r) * DD))[tid];
    float vx = b2f(v.x), vy = b2f(v.y);
    mxx = fmaxf(mxx, vx); mxy = fmaxf(mxy, vy);
    smx += vx; smy += vy;
  }
  int npad = Lh - lh;
  if (npad > 0){
    float2 p = ((const float2*)(padcmp + (size_t)b * DD))[tid];
    mxx = fmaxf(mxx, p.x); mxy = fmaxf(mxy, p.y);
    smx += npad * p.x; smy += npad * p.y;
  }
  float invLh = 1.f / (float)Lh;
  ((float2*)(smax + (size_t)b * DD))[tid] = make_float2(mxx, mxy);
  ((float2*)(smean + (size_t)b * DD))[tid] = make_float2(smx * invLh, smy * invLh);
}

__global__ __launch_bounds__(64) void logits_kernel(
    const float* __restrict__ z1, const float* __restrict__ c2, const float* __restrict__ cb2,
    float* __restrict__ out, int B)
{
  int b = blockIdx.x; int lane = threadIdx.x;
  const float4* zr = (const float4*)(z1 + (size_t)b * DD);
  float4 z0 = zr[lane*2], z1v = zr[lane*2+1];
  float zz[8] = {z0.x, z0.y, z0.z, z0.w, z1v.x, z1v.y, z1v.z, z1v.w};
  float p0 = 0.f, p1 = 0.f, p2 = 0.f;
  #pragma unroll
  for (int j = 0; j < 8; j++){
    int k = lane*8 + j;
    p0 += zz[j] * c2[k*3 + 0];
    p1 += zz[j] * c2[k*3 + 1];
    p2 += zz[j] * c2[k*3 + 2];
  }
  for (int off = 32; off; off >>= 1){
    p0 += __shfl_xor(p0, off); p1 += __shfl_xor(p1, off); p2 += __shfl_xor(p2, off);
  }
  if (lane == 0){
    out[1 + b*3 + 0] = p0 + cb2[0];
    out[1 + b*3 + 1] = p1 + cb2[1];
    out[1 + b*3 + 2] = p2 + cb2[2];
  }
}

__global__ __launch_bounds__(256) void loss_kernel(
    const float* __restrict__ dout, const float* __restrict__ label, float* __restrict__ out0, int n)
{
  __shared__ float red[256];
  int tid = threadIdx.x;
  float s = 0.f;
  for (int i = tid; i < n; i += 256){
    float z = dout[1 + i], y = label[i];
    s += fmaxf(z, 0.f) - z*y + log1pf(expf(-fabsf(z)));
  }
  red[tid] = s; __syncthreads();
  for (int st = 128; st; st >>= 1){ if (tid < st) red[tid] += red[tid+st]; __syncthreads(); }
  if (tid == 0) out0[0] = red[0] / (float)n;
}

// ------------------------------------------------------------------
extern "C" void kernel_launch(void* const* d_in, const int* in_sizes, int n_in,
                              void* d_out, int out_size, void* d_ws, size_t ws_size,
                              hipStream_t stream)
{
  const float* emb   = (const float*)d_in[0];
  const float* Wgat  = (const float*)d_in[1];
  const float* att_s = (const float*)d_in[2];
  const float* att_d = (const float*)d_in[3];
  const float* gbias = (const float*)d_in[4];
  const float* Wq    = (const float*)d_in[5];
  const float* Wk    = (const float*)d_in[6];
  const float* Wv    = (const float*)d_in[7];
  const float* w1    = (const float*)d_in[8];
  const float* b1    = (const float*)d_in[9];
  const float* w2    = (const float*)d_in[10];
  const float* b2    = (const float*)d_in[11];
  const float* c1    = (const float*)d_in[12];
  const float* cb1   = (const float*)d_in[13];
  const float* c2    = (const float*)d_in[14];
  const float* cb2   = (const float*)d_in[15];
  const float* label = (const float*)d_in[16];
  const int* xp = (const int*)d_in[17];
  const int* xh = (const int*)d_in[18];
  const int* ep = (const int*)d_in[19];
  const int* eh = (const int*)d_in[20];
  const int* bp = (const int*)d_in[21];
  const int* bh = (const int*)d_in[22];

  const int NP  = in_sizes[17], NH = in_sizes[18];
  const int N   = NP + NH;
  const int E2P = in_sizes[19] / 2, E2H = in_sizes[20] / 2;
  const int EALL = E2P + E2H + N;
  const int B = in_sizes[16] / 3;

  char* wptr = (char*)d_ws;
  auto alloc = [&](size_t bytes) -> void* {
    void* p = (void*)wptr; wptr += (bytes + 255) & ~(size_t)255; return p;
  };
  bf16* bufX = (bf16*)alloc((size_t)N  * DD * 2);  // node features / enc; p-half later = S,P
  bf16* bufY = (bf16*)alloc((size_t)N  * DD * 2);  // xw ; K ; Vt ; hidden
  bf16* bufV = (bf16*)alloc((size_t)NP * DD * 2);  // V ; later cmp
  bf16* bufQ = (bf16*)alloc((size_t)NH * DD * 2);  // Q ; later p_hat*h
  bf16* bufP = (bf16*)alloc((size_t)NH * DD * 2);  // p_hat
  float* a_s  = (float*)alloc((size_t)N * 8 * 4);
  float* a_d  = (float*)alloc((size_t)N * 8 * 4);
  int* counts   = (int*)alloc((size_t)N * 4);
  int* csr_off  = (int*)alloc((size_t)(N + 1) * 4);
  int* cursor   = (int*)alloc((size_t)N * 4);
  int* csr_src  = (int*)alloc((size_t)EALL * 4);
  int* bsums    = (int*)alloc(1024 * 4);
  int* starts_p = (int*)alloc((size_t)(B + 1) * 4);
  int* starts_h = (int*)alloc((size_t)(B + 1) * 4);
  int* devL     = (int*)alloc(64);
  float* padphat = (float*)alloc((size_t)B * DD * 4);
  float* padhid  = (float*)alloc((size_t)B * DD * 4);
  float* padcmp  = (float*)alloc((size_t)B * DD * 4);
  float* smax  = (float*)alloc((size_t)B * DD * 4);
  float* smean = (float*)alloc((size_t)B * DD * 4);
  float* z1    = (float*)alloc((size_t)B * DD * 4);
  float* Wpc   = (float*)alloc((size_t)DD * DD * 4);
  float* Whc   = (float*)alloc((size_t)DD * DD * 4);
  bf16* WT_gat = (bf16*)alloc((size_t)DD * DD * 2);
  bf16* WT_q   = (bf16*)alloc((size_t)DD * DD * 2);
  bf16* WT_k   = (bf16*)alloc((size_t)DD * DD * 2);
  bf16* WT_v   = (bf16*)alloc((size_t)DD * DD * 2);
  bf16* WT_pc  = (bf16*)alloc((size_t)DD * DD * 2);
  bf16* WT_hc  = (bf16*)alloc((size_t)DD * DD * 2);
  bf16* WT_1d  = (bf16*)alloc((size_t)DD * DD * 2);
  bf16* WT_2   = (bf16*)alloc((size_t)DD * DD * 2);

  hipMemsetAsync(counts, 0, (size_t)N * 4, stream);
  hipMemsetAsync(cursor, 0, (size_t)N * 4, stream);

  embed_kernel<<<N, 128, 0, stream>>>(emb, xp, xh, bufX, NP, N);
  mark_starts<<<(NP + 255)/256, 256, 0, stream>>>(bp, starts_p, NP, B);
  mark_starts<<<(NH + 255)/256, 256, 0, stream>>>(bh, starts_h, NH, B);
  compute_maxlen<<<1, 256, 0, stream>>>(starts_p, starts_h, B, devL);
  edge_count<<<(EALL + 255)/256, 256, 0, stream>>>(ep, eh, E2P, E2H, NP, N, counts);

  // hierarchical exclusive scan of counts -> csr_off[0..N], total in csr_off[N]
  int nb = (N + 2047) / 2048;
  scan_partial<<<nb, 256, 0, stream>>>(counts, csr_off, bsums, N);
  scan_sums<<<1, 1024, 0, stream>>>(bsums, nb, csr_off + N);
  scan_add<<<nb, 256, 0, stream>>>(csr_off, bsums, N);

  edge_fill<<<(EALL + 255)/256, 256, 0, stream>>>(ep, eh, E2P, E2H, NP, N, csr_off, cursor, csr_src);
  wcomb_kernel<<<(DD*DD + 255)/256, 256, 0, stream>>>(w1, Wpc, Whc);

  dim3 tg(8, 8);
  transpose_w<<<tg, 256, 0, stream>>>(Wgat, WT_gat);
  transpose_w<<<tg, 256, 0, stream>>>(Wq,   WT_q);
  transpose_w<<<tg, 256, 0, stream>>>(Wk,   WT_k);
  transpose_w<<<tg, 256, 0, stream>>>(Wv,   WT_v);
  transpose_w<<<tg, 256, 0, stream>>>(Wpc,  WT_pc);
  transpose_w<<<tg, 256, 0, stream>>>(Whc,  WT_hc);
  transpose_w<<<tg, 256, 0, stream>>>(w1 + (size_t)3*DD*DD, WT_1d);
  transpose_w<<<tg, 256, 0, stream>>>(w2,   WT_2);

  auto gemmM = [&](const bf16* A, const bf16* WT, const float* bias, bf16* Cv, int M, int flags){
    dim3 g((unsigned)((M + 127)/128), 4);
    gemm_mfma<<<g, 256, 0, stream>>>(A, WT, bias, Cv, M, flags);
  };
  auto gemmF = [&](const float* A, const float* Wm, const float* bias, float* Cv, int M, int flags){
    dim3 g((unsigned)((M + 63)/64), DD/64);
    gemm64<<<g, 256, 0, stream>>>(A, Wm, bias, Cv, M, DD, flags);
  };

  // 3 shared-weight GAT layers on the combined graph
  for (int l = 0; l < 3; l++){
    gemmM(bufX, WT_gat, nullptr, bufY, N, 0);
    gat_attn_coeff<<<N, 64, 0, stream>>>(bufY, att_s, att_d, a_s, a_d, N);
    gat_aggregate<<<N, 64, 0, stream>>>(bufY, a_s, a_d, csr_off, csr_src, gbias, bufX, N);
  }

  const bf16* h_enc = bufX + (size_t)NP * DD;
  gemmM(h_enc, WT_q, nullptr, bufQ, NH, 0);
  gemmM(bufX,  WT_k, nullptr, bufY, NP, 0);   // K
  gemmM(bufX,  WT_v, nullptr, bufV, NP, 0);   // V

  // --- MFMA cross-attention ---
  float* Sbuf = (float*)bufX;                               // [NH][384] f32
  bf16*  Pbuf = (bf16*)((char*)bufX + (((size_t)NH*384*4 + 255) & ~(size_t)255)); // [NH][416] bf16
  const int NPpad = (NP + 384 + 63) & ~63;
  bf16* Vt = bufY;

  score_mfma<<<dim3(B, 2, 6), 256, 0, stream>>>(bufQ, bufY, starts_p, starts_h, Sbuf, NH, NP);
  transpose_v<<<dim3((NP + 63)/64, 8), 256, 0, stream>>>(bufV, Vt, NP, NPpad);
  softmax_rows<<<(NH + 3)/4, 256, 0, stream>>>(Sbuf, Pbuf, starts_p, bh, NH);
  pv_mfma<<<dim3(B, 2, 4), 256, 0, stream>>>(Pbuf, Vt, starts_p, starts_h, bufP, NH, NPpad);
  vsum_kernel<<<B, 256, 0, stream>>>(bufV, starts_p, devL, padphat);

  size_t n8 = (size_t)NH * (DD/8);
  prod_kernel<<<(unsigned)((n8 + 255)/256), 256, 0, stream>>>(bufP, h_enc, bufQ, n8);

  bf16* hid = bufY;                        // Vt is dead after pv_mfma
  gemmM(bufP, WT_pc, b1, hid, NH, 0);
  gemmM(h_enc, WT_hc, nullptr, hid, NH, 1);
  gemmM(bufQ, WT_1d, nullptr, hid, NH, 1 | 2);  // + relu
  bf16* cmp = bufV;                        // V is dead
  gemmM(hid, WT_2, b2, cmp, NH, 0);

  gemmF(padphat, Wpc, b1, padhid, B, 2);   // pad rows: feat = [p,0,p,0]
  gemmF(padhid, w2, b2, padcmp, B, 0);

  pool_kernel<<<B, 256, 0, stream>>>(cmp, padcmp, starts_h, devL, smax, smean);

  gemmF(smax,  c1,                 cb1,     z1, B, 0);
  gemmF(smean, c1 + (size_t)DD*DD, nullptr, z1, B, 1 | 2);
  logits_kernel<<<B, 64, 0, stream>>>(z1, c2, cb2, (float*)d_out, B);
  loss_kernel<<<1, 256, 0, stream>>>((float*)d_out, label, (float*)d_out, B * 3);
}

// Round 10
// 1795.994 us; speedup vs baseline: 2.7651x; 1.0057x over previous
//
#include <hip/hip_runtime.h>
#include <cstdint>
#include <cstddef>

#define DD 512
#define SLOPE 0.2f

typedef unsigned short bf16;
typedef __attribute__((ext_vector_type(8))) short short8v;  // 8 bf16 (4 VGPRs)
typedef __attribute__((ext_vector_type(4))) float f32x4;

__device__ __forceinline__ float b2f(unsigned short u){
  union { float f; unsigned int i; } v; v.i = ((unsigned int)u) << 16; return v.f;
}
__device__ __forceinline__ unsigned short f2b(float f){
  union { float f; unsigned int i; } v; v.f = f;
  unsigned int r = v.i + 0x7FFFu + ((v.i >> 16) & 1u);
  return (unsigned short)(r >> 16);
}
__device__ __forceinline__ void unpack8(uint4 u, float* f){
  f[0]=b2f((unsigned short)(u.x & 0xFFFFu)); f[1]=b2f((unsigned short)(u.x >> 16));
  f[2]=b2f((unsigned short)(u.y & 0xFFFFu)); f[3]=b2f((unsigned short)(u.y >> 16));
  f[4]=b2f((unsigned short)(u.z & 0xFFFFu)); f[5]=b2f((unsigned short)(u.z >> 16));
  f[6]=b2f((unsigned short)(u.w & 0xFFFFu)); f[7]=b2f((unsigned short)(u.w >> 16));
}
__device__ __forceinline__ uint4 pack8(const float* f){
  uint4 u;
  u.x = (unsigned int)f2b(f[0]) | ((unsigned int)f2b(f[1]) << 16);
  u.y = (unsigned int)f2b(f[2]) | ((unsigned int)f2b(f[3]) << 16);
  u.z = (unsigned int)f2b(f[4]) | ((unsigned int)f2b(f[5]) << 16);
  u.w = (unsigned int)f2b(f[6]) | ((unsigned int)f2b(f[7]) << 16);
  return u;
}

// ------------------------------------------------------------------
__global__ __launch_bounds__(128) void embed_kernel(
    const float* __restrict__ emb, const int* __restrict__ xp, const int* __restrict__ xh,
    bf16* __restrict__ x, int NP, int N)
{
  int row = blockIdx.x; if (row >= N) return;
  int idx = (row < NP) ? xp[row] : xh[row - NP];
  float4 v = ((const float4*)(emb + (size_t)idx * DD))[threadIdx.x];
  ushort4 o; o.x = f2b(v.x); o.y = f2b(v.y); o.z = f2b(v.z); o.w = f2b(v.w);
  ((ushort4*)(x + (size_t)row * DD))[threadIdx.x] = o;
}

// ------------------------------------------------------------------
__global__ void mark_starts(const int* __restrict__ batch, int* __restrict__ starts, int n, int B)
{
  int i = blockIdx.x * blockDim.x + threadIdx.x; if (i >= n) return;
  int b = batch[i];
  if (i == 0) starts[0] = 0;
  else if (batch[i-1] != b) starts[b] = i;
  if (i == n-1) starts[B] = n;
}

__global__ __launch_bounds__(256) void compute_maxlen(
    const int* __restrict__ sp, const int* __restrict__ sh, int B, int* __restrict__ devL)
{
  __shared__ int red[256];
  int tid = threadIdx.x;
  int ml = 0;
  for (int b = tid; b < B; b += 256) ml = max(ml, sp[b+1]-sp[b]);
  red[tid] = ml; __syncthreads();
  for (int s = 128; s; s >>= 1){ if (tid < s) red[tid] = max(red[tid], red[tid+s]); __syncthreads(); }
  if (tid == 0) devL[0] = red[0];
  __syncthreads();
  ml = 0;
  for (int b = tid; b < B; b += 256) ml = max(ml, sh[b+1]-sh[b]);
  red[tid] = ml; __syncthreads();
  for (int s = 128; s; s >>= 1){ if (tid < s) red[tid] = max(red[tid], red[tid+s]); __syncthreads(); }
  if (tid == 0) devL[1] = red[0];
}

// ------------------------------------------------------------------
__global__ void edge_count(const int* __restrict__ ep, const int* __restrict__ eh,
                           int E2P, int E2H, int NP, int N, int* __restrict__ counts)
{
  int e = blockIdx.x * blockDim.x + threadIdx.x;
  int EALL = E2P + E2H + N;
  if (e >= EALL) return;
  int dst;
  if (e < E2P)            dst = ep[E2P + e];
  else if (e < E2P + E2H) dst = NP + eh[E2H + (e - E2P)];
  else                    dst = e - E2P - E2H;
  atomicAdd(&counts[dst], 1);
}

__global__ void edge_fill(const int* __restrict__ ep, const int* __restrict__ eh,
                          int E2P, int E2H, int NP, int N,
                          const int* __restrict__ off, int* __restrict__ cursor,
                          int* __restrict__ csr_src)
{
  int e = blockIdx.x * blockDim.x + threadIdx.x;
  int EALL = E2P + E2H + N;
  if (e >= EALL) return;
  int src, dst;
  if (e < E2P)            { src = ep[e];                 dst = ep[E2P + e]; }
  else if (e < E2P + E2H) { int j = e - E2P; src = NP + eh[j]; dst = NP + eh[E2H + j]; }
  else                    { src = dst = e - E2P - E2H; }
  int pos = atomicAdd(&cursor[dst], 1);
  csr_src[off[dst] + pos] = src;
}

// ------------------------------------------------------------------
// hierarchical exclusive scan: 2048 elems/block
__global__ __launch_bounds__(256) void scan_partial(
    const int* __restrict__ in, int* __restrict__ out, int* __restrict__ bsums, int n)
{
  __shared__ int wsum[4];
  int blk = blockIdx.x, tid = threadIdx.x;
  int base = blk * 2048 + tid * 8;
  int v[8]; int s = 0;
  #pragma unroll
  for (int j = 0; j < 8; j++){
    v[j] = (base + j < n) ? in[base + j] : 0;
    s += v[j];
  }
  int lane = tid & 63, wid = tid >> 6;
  int x = s;
  for (int off = 1; off < 64; off <<= 1){
    int y = __shfl_up(x, off);
    if (lane >= off) x += y;
  }
  if (lane == 63) wsum[wid] = x;
  __syncthreads();
  if (tid == 0){
    int acc = 0;
    #pragma unroll
    for (int w = 0; w < 4; w++){ int t = wsum[w]; wsum[w] = acc; acc += t; }
    bsums[blk] = acc;
  }
  __syncthreads();
  int run = x - s + wsum[wid];   // exclusive prefix of this thread within block
  #pragma unroll
  for (int j = 0; j < 8; j++){
    if (base + j < n) out[base + j] = run;
    run += v[j];
  }
}

// scan block sums (nb <= 1024) exclusive in-place; write grand total to *total
__global__ __launch_bounds__(1024) void scan_sums(int* __restrict__ bsums, int nb, int* __restrict__ total)
{
  __shared__ int buf[1024];
  int tid = threadIdx.x;
  int x = (tid < nb) ? bsums[tid] : 0;
  buf[tid] = x;
  __syncthreads();
  for (int off = 1; off < 1024; off <<= 1){
    int v = (tid >= off) ? buf[tid - off] : 0;
    __syncthreads();
    buf[tid] += v;
    __syncthreads();
  }
  if (tid < nb) bsums[tid] = buf[tid] - x;
  if (tid == 0) total[0] = buf[nb - 1];
}

__global__ __launch_bounds__(256) void scan_add(int* __restrict__ out, const int* __restrict__ bsums, int n)
{
  int blk = blockIdx.x;
  int base = blk * 2048 + threadIdx.x * 8;
  int add = bsums[blk];
  #pragma unroll
  for (int j = 0; j < 8; j++){
    if (base + j < n) out[base + j] += add;
  }
}

// ------------------------------------------------------------------
// 64x64-tile transpose + f32->bf16: dst[n][k] = bf16(src[k][n]); both 512x512
__global__ __launch_bounds__(256) void transpose_w(const float* __restrict__ src, bf16* __restrict__ dst)
{
  __shared__ float t[64][65];
  int k0 = blockIdx.x * 64, n0 = blockIdx.y * 64;
  int tid = threadIdx.x;
  int r = tid >> 4, c4 = (tid & 15) * 4;
  #pragma unroll
  for (int p = 0; p < 4; p++){
    int row = r + p*16;
    float4 v = *(const float4*)(src + (size_t)(k0 + row) * DD + n0 + c4);
    t[c4+0][row] = v.x; t[c4+1][row] = v.y; t[c4+2][row] = v.z; t[c4+3][row] = v.w;
  }
  __syncthreads();
  #pragma unroll
  for (int p = 0; p < 4; p++){
    int row = r + p*16;  // n-within-tile
    ushort4 o;
    o.x = f2b(t[row][c4+0]); o.y = f2b(t[row][c4+1]);
    o.z = f2b(t[row][c4+2]); o.w = f2b(t[row][c4+3]);
    *(ushort4*)(dst + (size_t)(n0 + row) * DD + k0 + c4) = o;
  }
}

// bf16 [NP][512] -> bf16 [512][NPpad] transpose (Vt for PV MFMA)
__global__ __launch_bounds__(256) void transpose_v(
    const bf16* __restrict__ V, bf16* __restrict__ Vt, int NP, int NPpad)
{
  __shared__ bf16 t[64][72];
  int r0 = blockIdx.x * 64, c0 = blockIdx.y * 64;
  int tid = threadIdx.x;
  int row = tid >> 2, cc = (tid & 3) * 16;
  uint4 v0 = {0,0,0,0}, v1 = {0,0,0,0};
  if (r0 + row < NP){
    v0 = *(const uint4*)(V + (size_t)(r0+row) * DD + c0 + cc);
    v1 = *(const uint4*)(V + (size_t)(r0+row) * DD + c0 + cc + 8);
  }
  *(uint4*)&t[row][cc]   = v0;
  *(uint4*)&t[row][cc+8] = v1;
  __syncthreads();
  int col = tid >> 2, rr = (tid & 3) * 16;
  ushort o[16];
  #pragma unroll
  for (int j = 0; j < 16; j++) o[j] = t[rr + j][col];
  *(uint4*)(Vt + (size_t)(c0+col) * NPpad + r0 + rr)     = *(uint4*)&o[0];
  *(uint4*)(Vt + (size_t)(c0+col) * NPpad + r0 + rr + 8) = *(uint4*)&o[8];
}

// ------------------------------------------------------------------
// MFMA bf16 GEMM: C[M,512] = A[M,512] @ W[512,512] (+bias)(+=C)(relu)
// col0 from blockIdx.x (4 tiles), row0 from blockIdx.y -> consecutive blocks
// share the same A panel for L2 locality.
// Staging via global_load_lds: LDS dest linear (base+lane*16), global source
// pre-swizzled by the (row&7)<<4 XOR -> LDS layout identical to the swizzled
// ds_write version; read side unchanged.
__global__ __launch_bounds__(256) void gemm_mfma(
    const bf16* __restrict__ A, const bf16* __restrict__ WT, const float* __restrict__ bias,
    bf16* __restrict__ C, int M, int flags)
{
  __shared__ __align__(16) bf16 Asub[128*64];
  __shared__ __align__(16) bf16 Bsub[128*64];
  int tid = threadIdx.x;
  int wave = tid >> 6, lane = tid & 63;
  int wr = wave >> 1, wc = wave & 1;
  int col0 = blockIdx.x * 128, row0 = blockIdx.y * 128;
  int l15 = lane & 15, l4 = lane >> 4;
  f32x4 acc[4][4];
  #pragma unroll
  for (int m = 0; m < 4; m++)
    #pragma unroll
    for (int n = 0; n < 4; n++)
      acc[m][n] = (f32x4){0.f, 0.f, 0.f, 0.f};

  int srow = lane >> 3;                       // 0..7 within 8-row chunk
  int cbyte = ((lane & 7) << 4) ^ (srow << 4); // swizzled source byte offset in 128B row

  for (int k0 = 0; k0 < DD; k0 += 64){
    #pragma unroll
    for (int pass = 0; pass < 4; pass++){
      int r0 = pass*32 + wave*8;              // wave-uniform row base
      int rr = r0 + srow;
      const char* ga = (const char*)(A  + (size_t)(row0 + rr) * DD + k0) + cbyte;
      const char* gb = (const char*)(WT + (size_t)(col0 + rr) * DD + k0) + cbyte;
      __builtin_amdgcn_global_load_lds(
          (const __attribute__((address_space(1))) unsigned int*)ga,
          (__attribute__((address_space(3))) unsigned int*)((char*)Asub + r0*128), 16, 0, 0);
      __builtin_amdgcn_global_load_lds(
          (const __attribute__((address_space(1))) unsigned int*)gb,
          (__attribute__((address_space(3))) unsigned int*)((char*)Bsub + r0*128), 16, 0, 0);
    }
    __syncthreads();
    #pragma unroll
    for (int kk = 0; kk < 2; kk++){
      int colb = kk*64 + (l4<<4);
      short8v af[4], bfr[4];
      #pragma unroll
      for (int m = 0; m < 4; m++){
        int ar = wr*64 + m*16 + l15;
        af[m]  = *(const short8v*)((const char*)Asub + ar*128 + (colb ^ ((ar&7)<<4)));
        int br = wc*64 + m*16 + l15;
        bfr[m] = *(const short8v*)((const char*)Bsub + br*128 + (colb ^ ((br&7)<<4)));
      }
      #pragma unroll
      for (int m = 0; m < 4; m++)
        #pragma unroll
        for (int n = 0; n < 4; n++)
          acc[m][n] = __builtin_amdgcn_mfma_f32_16x16x32_bf16(af[m], bfr[n], acc[m][n], 0, 0, 0);
    }
    __syncthreads();
  }

  #pragma unroll
  for (int m = 0; m < 4; m++){
    #pragma unroll
    for (int n = 0; n < 4; n++){
      int gc = col0 + wc*64 + n*16 + l15;
      float bv = bias ? bias[gc] : 0.f;
      #pragma unroll
      for (int r = 0; r < 4; r++){
        int gr = row0 + wr*64 + m*16 + l4*4 + r;
        if (gr < M){
          float v = acc[m][n][r] + bv;
          bf16* cp = C + (size_t)gr * DD + gc;
          if (flags & 1) v += b2f(*cp);
          if (flags & 2) v = fmaxf(v, 0.f);
          *cp = f2b(v);
        }
      }
    }
  }
}

// ------------------------------------------------------------------
// scores S[sh+r][c] = Q[sh+r,:] . K[sp+c,:]  (per-graph 64x64 tiles)
__global__ __launch_bounds__(256) void score_mfma(
    const bf16* __restrict__ Q, const bf16* __restrict__ K,
    const int* __restrict__ sp_arr, const int* __restrict__ sh_arr,
    float* __restrict__ S, int NH, int NP)
{
  int b = blockIdx.x;
  int sh = sh_arr[b], lh = sh_arr[b+1] - sh;
  int sp = sp_arr[b], lp = sp_arr[b+1] - sp;
  int qt = blockIdx.y * 64, kt = blockIdx.z * 64;
  if (qt >= lh || kt >= lp) return;
  int tid = threadIdx.x, wave = tid >> 6, lane = tid & 63;
  int wr = (wave >> 1) * 32, wc = (wave & 1) * 32;
  int l15 = lane & 15, l4 = lane >> 4;
  f32x4 acc[2][2];
  #pragma unroll
  for (int m = 0; m < 2; m++)
    #pragma unroll
    for (int n = 0; n < 2; n++)
      acc[m][n] = (f32x4){0.f,0.f,0.f,0.f};
  int ar[2], br[2];
  #pragma unroll
  for (int m = 0; m < 2; m++) ar[m] = min(sh + qt + wr + m*16 + l15, NH-1);
  #pragma unroll
  for (int n = 0; n < 2; n++) br[n] = min(sp + kt + wc + n*16 + l15, NP-1);
  for (int k0 = 0; k0 < DD; k0 += 32){
    short8v af[2], bv[2];
    #pragma unroll
    for (int m = 0; m < 2; m++) af[m] = *(const short8v*)(Q + (size_t)ar[m]*DD + k0 + l4*8);
    #pragma unroll
    for (int n = 0; n < 2; n++) bv[n] = *(const short8v*)(K + (size_t)br[n]*DD + k0 + l4*8);
    #pragma unroll
    for (int m = 0; m < 2; m++)
      #pragma unroll
      for (int n = 0; n < 2; n++)
        acc[m][n] = __builtin_amdgcn_mfma_f32_16x16x32_bf16(af[m], bv[n], acc[m][n], 0, 0, 0);
  }
  #pragma unroll
  for (int m = 0; m < 2; m++)
    #pragma unroll
    for (int n = 0; n < 2; n++)
      #pragma unroll
      for (int i = 0; i < 4; i++){
        int rr = qt + wr + m*16 + l4*4 + i;
        int cc = kt + wc + n*16 + l15;
        if (rr < lh && cc < lp) S[(size_t)(sh+rr)*384 + cc] = acc[m][n][i];
      }
}

// masked softmax over S rows -> P bf16, shifted by d = sp&7 (stride 416)
__global__ __launch_bounds__(256) void softmax_rows(
    const float* __restrict__ S, bf16* __restrict__ P,
    const int* __restrict__ sp_arr, const int* __restrict__ hbatch, int NH)
{
  __shared__ float sm[4][384];
  int w = threadIdx.x >> 6, lane = threadIdx.x & 63;
  int i = blockIdx.x * 4 + w; if (i >= NH) return;
  int b = hbatch[i];
  int sp = sp_arr[b], lp = sp_arr[b+1] - sp;
  int d = sp & 7;
  const float scale = 0.044194173824159216f; // 1/sqrt(512)
  float e[6]; float mx = -3.4e38f;
  #pragma unroll
  for (int j = 0; j < 6; j++){
    int c = j*64 + lane;
    float v = (c < lp) ? S[(size_t)i*384 + c] * scale : -1e30f;
    e[j] = v; mx = fmaxf(mx, v);
  }
  for (int off = 32; off; off >>= 1) mx = fmaxf(mx, __shfl_xor(mx, off));
  float sum = 0.f;
  #pragma unroll
  for (int j = 0; j < 6; j++){ float x = __expf(e[j] - mx); e[j] = x; sum += x; }
  for (int off = 32; off; off >>= 1) sum += __shfl_xor(sum, off);
  float inv = 1.f / sum;
  #pragma unroll
  for (int j = 0; j < 6; j++) sm[w][j*64 + lane] = e[j];
  #pragma unroll
  for (int j = 0; j < 7; j++){
    int o = j*64 + lane;
    if (o < 416){
      int c = o - d;
      float val = (c >= 0 && c < lp) ? sm[w][c] * inv : 0.f;
      P[(size_t)i*416 + o] = f2b(val);
    }
  }
}

// p_hat[sh+r][col] = sum_k P[sh+r][k] * Vt[col][jp0+k]
__global__ __launch_bounds__(256) void pv_mfma(
    const bf16* __restrict__ P, const bf16* __restrict__ Vt,
    const int* __restrict__ sp_arr, const int* __restrict__ sh_arr,
    bf16* __restrict__ out, int NH, int NPpad)
{
  int b = blockIdx.x;
  int sh = sh_arr[b], lh = sh_arr[b+1] - sh;
  int sp = sp_arr[b], lp = sp_arr[b+1] - sp;
  int qt = blockIdx.y * 64;
  if (qt >= lh) return;
  int ct = blockIdx.z * 128;
  int d = sp & 7, jp0 = sp - d;
  int tid = threadIdx.x, wave = tid >> 6, lane = tid & 63;
  int wr = (wave >> 1) * 32, wc = (wave & 1) * 64;
  int l15 = lane & 15, l4 = lane >> 4;
  f32x4 acc[2][4];
  #pragma unroll
  for (int m = 0; m < 2; m++)
    #pragma unroll
    for (int n = 0; n < 4; n++)
      acc[m][n] = (f32x4){0.f,0.f,0.f,0.f};
  int ar[2];
  #pragma unroll
  for (int m = 0; m < 2; m++) ar[m] = min(sh + qt + wr + m*16 + l15, NH-1);
  int kmax = (lp + d + 31) & ~31;
  for (int k0 = 0; k0 < kmax; k0 += 32){
    short8v af[2], bv[4];
    #pragma unroll
    for (int m = 0; m < 2; m++) af[m] = *(const short8v*)(P + (size_t)ar[m]*416 + k0 + l4*8);
    #pragma unroll
    for (int n = 0; n < 4; n++){
      int vc = ct + wc + n*16 + l15;
      bv[n] = *(const short8v*)(Vt + (size_t)vc*NPpad + jp0 + k0 + l4*8);
    }
    #pragma unroll
    for (int m = 0; m < 2; m++)
      #pragma unroll
      for (int n = 0; n < 4; n++)
        acc[m][n] = __builtin_amdgcn_mfma_f32_16x16x32_bf16(af[m], bv[n], acc[m][n], 0, 0, 0);
  }
  #pragma unroll
  for (int m = 0; m < 2; m++)
    #pragma unroll
    for (int n = 0; n < 4; n++)
      #pragma unroll
      for (int i = 0; i < 4; i++){
        int rr = qt + wr + m*16 + l4*4 + i;
        int cc = ct + wc + n*16 + l15;
        if (rr < lh) out[(size_t)(sh+rr)*DD + cc] = f2b(acc[m][n][i]);
      }
}

// ------------------------------------------------------------------
// f32 tiled GEMM (small-M paths only: pad rows, classifier)
__global__ __launch_bounds__(256) void gemm64(
    const float* __restrict__ A, const float* __restrict__ W, const float* __restrict__ bias,
    float* __restrict__ C, int M, int Ncol, int flags)
{
  __shared__ float As[16][65];
  __shared__ float Bs[16][64];
  int tid = threadIdx.x;
  int tx = tid & 15, ty = tid >> 4;
  int row0 = blockIdx.x * 64, col0 = blockIdx.y * 64;
  float acc[4][4] = {};
  int lr = tid >> 2, lk = (tid & 3) * 4;
  int bk = tid >> 4, bn = (tid & 15) * 4;
  for (int k0 = 0; k0 < DD; k0 += 16){
    float a0 = 0.f, a1 = 0.f, a2 = 0.f, a3 = 0.f;
    int gr = row0 + lr;
    if (gr < M){
      float4 av = *(const float4*)(A + (size_t)gr * DD + k0 + lk);
      a0 = av.x; a1 = av.y; a2 = av.z; a3 = av.w;
    }
    As[lk+0][lr] = a0; As[lk+1][lr] = a1; As[lk+2][lr] = a2; As[lk+3][lr] = a3;
    *(float4*)&Bs[bk][bn] = *(const float4*)(W + (size_t)(k0 + bk) * Ncol + col0 + bn);
    __syncthreads();
    #pragma unroll
    for (int k = 0; k < 16; k++){
      float x0 = As[k][ty*4+0], x1 = As[k][ty*4+1], x2 = As[k][ty*4+2], x3 = As[k][ty*4+3];
      float y0 = Bs[k][tx*4+0], y1 = Bs[k][tx*4+1], y2 = Bs[k][tx*4+2], y3 = Bs[k][tx*4+3];
      acc[0][0] += x0*y0; acc[0][1] += x0*y1; acc[0][2] += x0*y2; acc[0][3] += x0*y3;
      acc[1][0] += x1*y0; acc[1][1] += x1*y1; acc[1][2] += x1*y2; acc[1][3] += x1*y3;
      acc[2][0] += x2*y0; acc[2][1] += x2*y1; acc[2][2] += x2*y2; acc[2][3] += x2*y3;
      acc[3][0] += x3*y0; acc[3][1] += x3*y1; acc[3][2] += x3*y2; acc[3][3] += x3*y3;
    }
    __syncthreads();
  }
  #pragma unroll
  for (int i = 0; i < 4; i++){
    int gr = row0 + ty*4 + i; if (gr >= M) continue;
    float r0 = acc[i][0], r1 = acc[i][1], r2 = acc[i][2], r3 = acc[i][3];
    if (bias){
      float4 bv = *(const float4*)(bias + col0 + tx*4);
      r0 += bv.x; r1 += bv.y; r2 += bv.z; r3 += bv.w;
    }
    float4* cp = (float4*)(C + (size_t)gr * Ncol + col0 + tx*4);
    if (flags & 1){
      float4 o = *cp;
      r0 += o.x; r1 += o.y; r2 += o.z; r3 += o.w;
    }
    if (flags & 2){
      r0 = fmaxf(r0, 0.f); r1 = fmaxf(r1, 0.f); r2 = fmaxf(r2, 0.f); r3 = fmaxf(r3, 0.f);
    }
    *cp = make_float4(r0, r1, r2, r3);
  }
}

// ------------------------------------------------------------------
__global__ __launch_bounds__(64) void gat_attn_coeff(
    const bf16* __restrict__ xw, const float* __restrict__ att_src, const float* __restrict__ att_dst,
    float* __restrict__ a_s, float* __restrict__ a_d, int N)
{
  int n = blockIdx.x; if (n >= N) return;
  int lane = threadIdx.x;
  float x[8];
  unpack8(*(const uint4*)(xw + (size_t)n * DD + lane * 8), x);
  const float4* sr = (const float4*)(att_src + lane * 8);
  const float4* dr = (const float4*)(att_dst + lane * 8);
  float4 s0 = sr[0], s1 = sr[1], d0 = dr[0], d1 = dr[1];
  float ps = x[0]*s0.x + x[1]*s0.y + x[2]*s0.z + x[3]*s0.w
           + x[4]*s1.x + x[5]*s1.y + x[6]*s1.z + x[7]*s1.w;
  float pd = x[0]*d0.x + x[1]*d0.y + x[2]*d0.z + x[3]*d0.w
           + x[4]*d1.x + x[5]*d1.y + x[6]*d1.z + x[7]*d1.w;
  for (int off = 1; off < 8; off <<= 1){ ps += __shfl_xor(ps, off); pd += __shfl_xor(pd, off); }
  if ((lane & 7) == 0){
    a_s[n*8 + (lane>>3)] = ps;
    a_d[n*8 + (lane>>3)] = pd;
  }
}

__global__ __launch_bounds__(64) void gat_aggregate(
    const bf16* __restrict__ xw, const float* __restrict__ a_s, const float* __restrict__ a_d,
    const int* __restrict__ csr_off, const int* __restrict__ csr_src,
    const float* __restrict__ bias, bf16* __restrict__ out, int N)
{
  int n = blockIdx.x; if (n >= N) return;
  int lane = threadIdx.x;
  int h = lane >> 3;
  int o0 = csr_off[n], deg = csr_off[n+1] - o0;
  float adh = a_d[n*8 + h];
  float mx = -3.4e38f;
  for (int e = 0; e < deg; e++){
    int s = csr_src[o0 + e];
    float v = a_s[s*8 + h] + adh;
    v = (v >= 0.f) ? v : SLOPE * v;
    mx = fmaxf(mx, v);
  }
  float den = 0.f;
  for (int e = 0; e < deg; e++){
    int s = csr_src[o0 + e];
    float v = a_s[s*8 + h] + adh;
    v = (v >= 0.f) ? v : SLOPE * v;
    den += __expf(v - mx);
  }
  float inv = 1.f / (den + 1e-16f);
  float A[8] = {};
  for (int e = 0; e < deg; e++){
    int s = csr_src[o0 + e];
    float v = a_s[s*8 + h] + adh;
    v = (v >= 0.f) ? v : SLOPE * v;
    float al = __expf(v - mx) * inv;
    float x[8];
    unpack8(*(const uint4*)(xw + (size_t)s * DD + lane * 8), x);
    #pragma unroll
    for (int j = 0; j < 8; j++) A[j] += al * x[j];
  }
  const float4* bq = (const float4*)(bias + lane * 8);
  float4 b0 = bq[0], b1 = bq[1];
  float r[8] = { A[0]+b0.x, A[1]+b0.y, A[2]+b0.z, A[3]+b0.w,
                 A[4]+b1.x, A[5]+b1.y, A[6]+b1.z, A[7]+b1.w };
  *(uint4*)(out + (size_t)n * DD + lane * 8) = pack8(r);
}

// ------------------------------------------------------------------
__global__ __launch_bounds__(256) void vsum_kernel(
    const bf16* __restrict__ V, const int* __restrict__ sp_arr, const int* __restrict__ devL,
    float* __restrict__ padphat)
{
  int b = blockIdx.x, tid = threadIdx.x;
  int sp = sp_arr[b], lp = sp_arr[b+1] - sp;
  float ax = 0.f, ay = 0.f;
  for (int m = 0; m < lp; m++){
    ushort2 vv = ((const ushort2*)(V + (size_t)(sp + m) * DD))[tid];
    ax += b2f(vv.x); ay += b2f(vv.y);
  }
  float invLp = 1.f / (float)devL[0];
  ((float2*)(padphat + (size_t)b * DD))[tid] = make_float2(ax * invLp, ay * invLp);
}

__global__ void prod_kernel(const bf16* __restrict__ a, const bf16* __restrict__ b,
                            bf16* __restrict__ c, size_t n8)
{
  size_t i = (size_t)blockIdx.x * blockDim.x + threadIdx.x;
  if (i >= n8) return;
  float fa[8], fb[8], fc[8];
  unpack8(((const uint4*)a)[i], fa);
  unpack8(((const uint4*)b)[i], fb);
  #pragma unroll
  for (int j = 0; j < 8; j++) fc[j] = fa[j] * fb[j];
  ((uint4*)c)[i] = pack8(fc);
}

__global__ void wcomb_kernel(const float* __restrict__ w1, float* __restrict__ Wp, float* __restrict__ Wh)
{
  int i = blockIdx.x * blockDim.x + threadIdx.x;
  if (i >= DD*DD) return;
  float a = w1[i], b = w1[i + DD*DD], c = w1[i + 2*DD*DD];
  Wp[i] = a + c;
  Wh[i] = b - c;
}

__global__ __launch_bounds__(256) void pool_kernel(
    const bf16* __restrict__ cmp, const float* __restrict__ padcmp,
    const int* __restrict__ sh_arr, const int* __restrict__ devL,
    float* __restrict__ smax, float* __restrict__ smean)
{
  int b = blockIdx.x, tid = threadIdx.x;
  int sh = sh_arr[b], lh = sh_arr[b+1] - sh;
  int Lh = devL[1];
  float mxx = -3.4e38f, mxy = -3.4e38f, smx = 0.f, smy = 0.f;
  for (int r = 0; r < lh; r++){
    ushort2 v = ((const ushort2*)(cmp + (size_t)(sh + r) * DD))[tid];
    float vx = b2f(v.x), vy = b2f(v.y);
    mxx = fmaxf(mxx, vx); mxy = fmaxf(mxy, vy);
    smx += vx; smy += vy;
  }
  int npad = Lh - lh;
  if (npad > 0){
    float2 p = ((const float2*)(padcmp + (size_t)b * DD))[tid];
    mxx = fmaxf(mxx, p.x); mxy = fmaxf(mxy, p.y);
    smx += npad * p.x; smy += npad * p.y;
  }
  float invLh = 1.f / (float)Lh;
  ((float2*)(smax + (size_t)b * DD))[tid] = make_float2(mxx, mxy);
  ((float2*)(smean + (size_t)b * DD))[tid] = make_float2(smx * invLh, smy * invLh);
}

__global__ __launch_bounds__(64) void logits_kernel(
    const float* __restrict__ z1, const float* __restrict__ c2, const float* __restrict__ cb2,
    float* __restrict__ out, int B)
{
  int b = blockIdx.x; int lane = threadIdx.x;
  const float4* zr = (const float4*)(z1 + (size_t)b * DD);
  float4 z0 = zr[lane*2], z1v = zr[lane*2+1];
  float zz[8] = {z0.x, z0.y, z0.z, z0.w, z1v.x, z1v.y, z1v.z, z1v.w};
  float p0 = 0.f, p1 = 0.f, p2 = 0.f;
  #pragma unroll
  for (int j = 0; j < 8; j++){
    int k = lane*8 + j;
    p0 += zz[j] * c2[k*3 + 0];
    p1 += zz[j] * c2[k*3 + 1];
    p2 += zz[j] * c2[k*3 + 2];
  }
  for (int off = 32; off; off >>= 1){
    p0 += __shfl_xor(p0, off); p1 += __shfl_xor(p1, off); p2 += __shfl_xor(p2, off);
  }
  if (lane == 0){
    out[1 + b*3 + 0] = p0 + cb2[0];
    out[1 + b*3 + 1] = p1 + cb2[1];
    out[1 + b*3 + 2] = p2 + cb2[2];
  }
}

__global__ __launch_bounds__(256) void loss_kernel(
    const float* __restrict__ dout, const float* __restrict__ label, float* __restrict__ out0, int n)
{
  __shared__ float red[256];
  int tid = threadIdx.x;
  float s = 0.f;
  for (int i = tid; i < n; i += 256){
    float z = dout[1 + i], y = label[i];
    s += fmaxf(z, 0.f) - z*y + log1pf(expf(-fabsf(z)));
  }
  red[tid] = s; __syncthreads();
  for (int st = 128; st; st >>= 1){ if (tid < st) red[tid] += red[tid+st]; __syncthreads(); }
  if (tid == 0) out0[0] = red[0] / (float)n;
}

// ------------------------------------------------------------------
extern "C" void kernel_launch(void* const* d_in, const int* in_sizes, int n_in,
                              void* d_out, int out_size, void* d_ws, size_t ws_size,
                              hipStream_t stream)
{
  const float* emb   = (const float*)d_in[0];
  const float* Wgat  = (const float*)d_in[1];
  const float* att_s = (const float*)d_in[2];
  const float* att_d = (const float*)d_in[3];
  const float* gbias = (const float*)d_in[4];
  const float* Wq    = (const float*)d_in[5];
  const float* Wk    = (const float*)d_in[6];
  const float* Wv    = (const float*)d_in[7];
  const float* w1    = (const float*)d_in[8];
  const float* b1    = (const float*)d_in[9];
  const float* w2    = (const float*)d_in[10];
  const float* b2    = (const float*)d_in[11];
  const float* c1    = (const float*)d_in[12];
  const float* cb1   = (const float*)d_in[13];
  const float* c2    = (const float*)d_in[14];
  const float* cb2   = (const float*)d_in[15];
  const float* label = (const float*)d_in[16];
  const int* xp = (const int*)d_in[17];
  const int* xh = (const int*)d_in[18];
  const int* ep = (const int*)d_in[19];
  const int* eh = (const int*)d_in[20];
  const int* bp = (const int*)d_in[21];
  const int* bh = (const int*)d_in[22];

  const int NP  = in_sizes[17], NH = in_sizes[18];
  const int N   = NP + NH;
  const int E2P = in_sizes[19] / 2, E2H = in_sizes[20] / 2;
  const int EALL = E2P + E2H + N;
  const int B = in_sizes[16] / 3;

  char* wptr = (char*)d_ws;
  auto alloc = [&](size_t bytes) -> void* {
    void* p = (void*)wptr; wptr += (bytes + 255) & ~(size_t)255; return p;
  };
  bf16* bufX = (bf16*)alloc((size_t)N  * DD * 2);  // node features / enc; p-half later = S,P
  bf16* bufY = (bf16*)alloc((size_t)N  * DD * 2);  // xw ; K ; Vt ; hidden
  bf16* bufV = (bf16*)alloc((size_t)NP * DD * 2);  // V ; later cmp
  bf16* bufQ = (bf16*)alloc((size_t)NH * DD * 2);  // Q ; later p_hat*h
  bf16* bufP = (bf16*)alloc((size_t)NH * DD * 2);  // p_hat
  float* a_s  = (float*)alloc((size_t)N * 8 * 4);
  float* a_d  = (float*)alloc((size_t)N * 8 * 4);
  int* counts   = (int*)alloc((size_t)N * 4);
  int* csr_off  = (int*)alloc((size_t)(N + 1) * 4);
  int* cursor   = (int*)alloc((size_t)N * 4);
  int* csr_src  = (int*)alloc((size_t)EALL * 4);
  int* bsums    = (int*)alloc(1024 * 4);
  int* starts_p = (int*)alloc((size_t)(B + 1) * 4);
  int* starts_h = (int*)alloc((size_t)(B + 1) * 4);
  int* devL     = (int*)alloc(64);
  float* padphat = (float*)alloc((size_t)B * DD * 4);
  float* padhid  = (float*)alloc((size_t)B * DD * 4);
  float* padcmp  = (float*)alloc((size_t)B * DD * 4);
  float* smax  = (float*)alloc((size_t)B * DD * 4);
  float* smean = (float*)alloc((size_t)B * DD * 4);
  float* z1    = (float*)alloc((size_t)B * DD * 4);
  float* Wpc   = (float*)alloc((size_t)DD * DD * 4);
  float* Whc   = (float*)alloc((size_t)DD * DD * 4);
  bf16* WT_gat = (bf16*)alloc((size_t)DD * DD * 2);
  bf16* WT_q   = (bf16*)alloc((size_t)DD * DD * 2);
  bf16* WT_k   = (bf16*)alloc((size_t)DD * DD * 2);
  bf16* WT_v   = (bf16*)alloc((size_t)DD * DD * 2);
  bf16* WT_pc  = (bf16*)alloc((size_t)DD * DD * 2);
  bf16* WT_hc  = (bf16*)alloc((size_t)DD * DD * 2);
  bf16* WT_1d  = (bf16*)alloc((size_t)DD * DD * 2);
  bf16* WT_2   = (bf16*)alloc((size_t)DD * DD * 2);

  hipMemsetAsync(counts, 0, (size_t)N * 4, stream);
  hipMemsetAsync(cursor, 0, (size_t)N * 4, stream);

  embed_kernel<<<N, 128, 0, stream>>>(emb, xp, xh, bufX, NP, N);
  mark_starts<<<(NP + 255)/256, 256, 0, stream>>>(bp, starts_p, NP, B);
  mark_starts<<<(NH + 255)/256, 256, 0, stream>>>(bh, starts_h, NH, B);
  compute_maxlen<<<1, 256, 0, stream>>>(starts_p, starts_h, B, devL);
  edge_count<<<(EALL + 255)/256, 256, 0, stream>>>(ep, eh, E2P, E2H, NP, N, counts);

  // hierarchical exclusive scan of counts -> csr_off[0..N], total in csr_off[N]
  int nb = (N + 2047) / 2048;
  scan_partial<<<nb, 256, 0, stream>>>(counts, csr_off, bsums, N);
  scan_sums<<<1, 1024, 0, stream>>>(bsums, nb, csr_off + N);
  scan_add<<<nb, 256, 0, stream>>>(csr_off, bsums, N);

  edge_fill<<<(EALL + 255)/256, 256, 0, stream>>>(ep, eh, E2P, E2H, NP, N, csr_off, cursor, csr_src);
  wcomb_kernel<<<(DD*DD + 255)/256, 256, 0, stream>>>(w1, Wpc, Whc);

  dim3 tg(8, 8);
  transpose_w<<<tg, 256, 0, stream>>>(Wgat, WT_gat);
  transpose_w<<<tg, 256, 0, stream>>>(Wq,   WT_q);
  transpose_w<<<tg, 256, 0, stream>>>(Wk,   WT_k);
  transpose_w<<<tg, 256, 0, stream>>>(Wv,   WT_v);
  transpose_w<<<tg, 256, 0, stream>>>(Wpc,  WT_pc);
  transpose_w<<<tg, 256, 0, stream>>>(Whc,  WT_hc);
  transpose_w<<<tg, 256, 0, stream>>>(w1 + (size_t)3*DD*DD, WT_1d);
  transpose_w<<<tg, 256, 0, stream>>>(w2,   WT_2);

  auto gemmM = [&](const bf16* A, const bf16* WT, const float* bias, bf16* Cv, int M, int flags){
    dim3 g(4, (unsigned)((M + 127)/128));   // col tiles fastest -> shared A panel stays in same L2
    gemm_mfma<<<g, 256, 0, stream>>>(A, WT, bias, Cv, M, flags);
  };
  auto gemmF = [&](const float* A, const float* Wm, const float* bias, float* Cv, int M, int flags){
    dim3 g((unsigned)((M + 63)/64), DD/64);
    gemm64<<<g, 256, 0, stream>>>(A, Wm, bias, Cv, M, DD, flags);
  };

  // 3 shared-weight GAT layers on the combined graph
  for (int l = 0; l < 3; l++){
    gemmM(bufX, WT_gat, nullptr, bufY, N, 0);
    gat_attn_coeff<<<N, 64, 0, stream>>>(bufY, att_s, att_d, a_s, a_d, N);
    gat_aggregate<<<N, 64, 0, stream>>>(bufY, a_s, a_d, csr_off, csr_src, gbias, bufX, N);
  }

  const bf16* h_enc = bufX + (size_t)NP * DD;
  gemmM(h_enc, WT_q, nullptr, bufQ, NH, 0);
  gemmM(bufX,  WT_k, nullptr, bufY, NP, 0);   // K
  gemmM(bufX,  WT_v, nullptr, bufV, NP, 0);   // V

  // --- MFMA cross-attention ---
  float* Sbuf = (float*)bufX;                               // [NH][384] f32
  bf16*  Pbuf = (bf16*)((char*)bufX + (((size_t)NH*384*4 + 255) & ~(size_t)255)); // [NH][416] bf16
  const int NPpad = (NP + 384 + 63) & ~63;
  bf16* Vt = bufY;

  score_mfma<<<dim3(B, 2, 6), 256, 0, stream>>>(bufQ, bufY, starts_p, starts_h, Sbuf, NH, NP);
  transpose_v<<<dim3((NP + 63)/64, 8), 256, 0, stream>>>(bufV, Vt, NP, NPpad);
  softmax_rows<<<(NH + 3)/4, 256, 0, stream>>>(Sbuf, Pbuf, starts_p, bh, NH);
  pv_mfma<<<dim3(B, 2, 4), 256, 0, stream>>>(Pbuf, Vt, starts_p, starts_h, bufP, NH, NPpad);
  vsum_kernel<<<B, 256, 0, stream>>>(bufV, starts_p, devL, padphat);

  size_t n8 = (size_t)NH * (DD/8);
  prod_kernel<<<(unsigned)((n8 + 255)/256), 256, 0, stream>>>(bufP, h_enc, bufQ, n8);

  bf16* hid = bufY;                        // Vt is dead after pv_mfma
  gemmM(bufP, WT_pc, b1, hid, NH, 0);
  gemmM(h_enc, WT_hc, nullptr, hid, NH, 1);
  gemmM(bufQ, WT_1d, nullptr, hid, NH, 1 | 2);  // + relu
  bf16* cmp = bufV;                        // V is dead
  gemmM(hid, WT_2, b2, cmp, NH, 0);

  gemmF(padphat, Wpc, b1, padhid, B, 2);   // pad rows: feat = [p,0,p,0]
  gemmF(padhid, w2, b2, padcmp, B, 0);

  pool_kernel<<<B, 256, 0, stream>>>(cmp, padcmp, starts_h, devL, smax, smean);

  gemmF(smax,  c1,                 cb1,     z1, B, 0);
  gemmF(smean, c1 + (size_t)DD*DD, nullptr, z1, B, 1 | 2);
  logits_kernel<<<B, 64, 0, stream>>>(z1, c2, cb2, (float*)d_out, B);
  loss_kernel<<<1, 256, 0, stream>>>((float*)d_out, label, (float*)d_out, B * 3);
}